// Round 8
// baseline (3107.259 us; speedup 1.0000x reference)
//
#include <hip/hip_runtime.h>
#include <cstdint>
#include <cstddef>

#define B_GRAPHS 2048
#define N_NODES  64
#define FIN      49
#define D_DIM    256
#define H_HEADS  8
#define DK_DIM   32
#define L_LAYERS 6
#define ALPHA    0.2f

#define M_FULL     (B_GRAPHS * N_NODES)           // 131072 rows
#define WROWS      272                             // 256 W rows + 16 Wa rows
#define WSLAB      (WROWS * 256)                   // per-layer weight slab elems
#define GPB        4                               // graphs per block

typedef __bf16 bf16x8 __attribute__((ext_vector_type(8)));
typedef __bf16 bf16x4 __attribute__((ext_vector_type(4)));
typedef float  f32x4  __attribute__((ext_vector_type(4)));

#define MFMA16(a, b, c) __builtin_amdgcn_mfma_f32_16x16x32_bf16(a, b, c, 0, 0, 0)

__device__ __forceinline__ float leaky(float t) { return t > 0.f ? t : ALPHA * t; }

// ---------------------------------------------------------------------------
// Weight prep (round-5-verified): split W (+ Wa = W^T a rows) to bf16 hi/lo.
// ---------------------------------------------------------------------------
__global__ void convert_weights(const float* __restrict__ W_emb,
                                const float* __restrict__ gat_W,
                                const float* __restrict__ gat_a,
                                const float* __restrict__ gat_b,
                                __bf16* __restrict__ Whi_emb,
                                __bf16* __restrict__ Wlo_emb,
                                __bf16* __restrict__ Whi,
                                __bf16* __restrict__ Wlo,
                                float* __restrict__ ba)
{
    int idx = blockIdx.x * 256 + threadIdx.x;
    if (idx < 256 * 64) {
        int n = idx >> 6, k = idx & 63;
        float f = (k < FIN) ? W_emb[n * FIN + k] : 0.f;
        __bf16 hi = (__bf16)f;
        Whi_emb[idx] = hi;
        Wlo_emb[idx] = (__bf16)(f - (float)hi);
    }
    if (idx < L_LAYERS * 65536) {
        int l = idx >> 16, nk = idx & 65535;
        float f = gat_W[idx];
        __bf16 hi = (__bf16)f;
        int dst = l * WSLAB + nk;
        Whi[dst] = hi;
        Wlo[dst] = (__bf16)(f - (float)hi);
    }
    int o = idx - L_LAYERS * 65536;
    if (o >= 0 && o < L_LAYERS * 4096) {
        int l = o >> 12, r = o & 4095;
        int k = r >> 4, c = r & 15;
        int hh = c >> 1, sd = c & 1;
        const float* av = gat_a + l * 512 + hh * 64 + sd * 32;
        const float* wp = gat_W + ((size_t)l * 256 + hh * 32) * 256 + k;
        float s = 0.f;
        for (int d = 0; d < 32; d++) s += av[d] * wp[d * 256];
        int dst = l * WSLAB + (256 + c) * 256 + k;
        __bf16 hi = (__bf16)s;
        Whi[dst] = hi;
        Wlo[dst] = (__bf16)(s - (float)hi);
    }
    int o2 = idx - L_LAYERS * 65536 - L_LAYERS * 4096;
    if (o2 >= 0 && o2 < L_LAYERS * 16) {
        int l = o2 >> 4, c = o2 & 15;
        int hh = c >> 1, sd = c & 1;
        const float* av = gat_a + l * 512 + hh * 64 + sd * 32;
        const float* bp = gat_b + l * 256 + hh * 32;
        float s = 0.f;
        for (int d = 0; d < 32; d++) s += av[d] * bp[d];
        ba[o2] = s;
    }
}

// x [M][49] fp32 -> xhi/xlo [M][64] bf16 (zero-padded)
__global__ void convert_x(const float* __restrict__ x,
                          __bf16* __restrict__ xhi, __bf16* __restrict__ xlo)
{
    int idx = blockIdx.x * 256 + threadIdx.x;
    int m = idx >> 6, k = idx & 63;
    float f = (k < FIN) ? x[m * FIN + k] : 0.f;
    __bf16 hi = (__bf16)f;
    xhi[idx] = hi;
    xlo[idx] = (__bf16)(f - (float)hi);
}

// ---------------------------------------------------------------------------
// Adjacency bitmasks, once: masks[g][r] bit j = A[g][r][j] > 0.
// ---------------------------------------------------------------------------
__global__ void build_masks(const float* __restrict__ A,
                            unsigned long long* __restrict__ masks)
{
    int g = blockIdx.x;
    int lane = threadIdx.x & 63;
    int w = threadIdx.x >> 6;
    const float* Ab = A + (size_t)g * 4096;
    for (int rr = 0; rr < 16; rr++) {
        int r = w * 16 + rr;
        unsigned long long m = __ballot(Ab[r * 64 + lane] > 0.f);
        if (lane == 0) masks[g * 64 + r] = m;
    }
}

// ---------------------------------------------------------------------------
// Embed GEMM: hhi/hlo[M,256] = split(x @ W_emb^T), 3-term bf16 MFMA.
// ---------------------------------------------------------------------------
__device__ __forceinline__ int swz(int r, int s) {
    return r * 64 + (((s ^ (r & 3)) << 4));
}

__global__ __launch_bounds__(256, 2)
void gemm_embed(const __bf16* __restrict__ Ahi, const __bf16* __restrict__ Alo,
                const __bf16* __restrict__ Bhi, const __bf16* __restrict__ Blo,
                __bf16* __restrict__ Chi, __bf16* __restrict__ Clo)
{
    const int K = 64;
    __shared__ __align__(16) char lds[2][32768];

    const int tid  = threadIdx.x;
    const int m0   = blockIdx.x * 128;
    const int n0   = blockIdx.y * 128;
    const int lane = tid & 63;
    const int wid  = tid >> 6;
    const int wr   = wid >> 1, wc = wid & 1;

    bf16x8 regAh[2], regAl[2], regBh[2], regBl[2];
    f32x4 acc[4][4];
#pragma unroll
    for (int i = 0; i < 4; i++)
#pragma unroll
        for (int j = 0; j < 4; j++) acc[i][j] = (f32x4){0.f, 0.f, 0.f, 0.f};

    auto load_stage = [&](int k0) {
#pragma unroll
        for (int g = 0; g < 2; g++) {
            int u = g * 256 + tid, r = u >> 2, s = u & 3;
            regAh[g] = *(const bf16x8*)(Ahi + (size_t)(m0 + r) * K + k0 + s * 8);
            regAl[g] = *(const bf16x8*)(Alo + (size_t)(m0 + r) * K + k0 + s * 8);
            regBh[g] = *(const bf16x8*)(Bhi + (size_t)(n0 + r) * K + k0 + s * 8);
            regBl[g] = *(const bf16x8*)(Blo + (size_t)(n0 + r) * K + k0 + s * 8);
        }
    };
    auto write_stage = [&](int buf) {
        char* base = lds[buf];
#pragma unroll
        for (int g = 0; g < 2; g++) {
            int u = g * 256 + tid, r = u >> 2, s = u & 3;
            int off = swz(r, s);
            *(bf16x8*)(base + off)         = regAh[g];
            *(bf16x8*)(base + 8192 + off)  = regAl[g];
            *(bf16x8*)(base + 16384 + off) = regBh[g];
            *(bf16x8*)(base + 24576 + off) = regBl[g];
        }
    };
    auto compute = [&](int buf) {
        const char* base = lds[buf];
        const int s = lane >> 4;
        bf16x8 ah[4], al[4];
#pragma unroll
        for (int mf = 0; mf < 4; mf++) {
            int r = wr * 64 + mf * 16 + (lane & 15);
            int off = swz(r, s);
            ah[mf] = *(const bf16x8*)(base + off);
            al[mf] = *(const bf16x8*)(base + 8192 + off);
        }
#pragma unroll
        for (int nf = 0; nf < 4; nf++) {
            int r = wc * 64 + nf * 16 + (lane & 15);
            int off = swz(r, s);
            bf16x8 bh = *(const bf16x8*)(base + 16384 + off);
            bf16x8 bl = *(const bf16x8*)(base + 24576 + off);
#pragma unroll
            for (int mf = 0; mf < 4; mf++) {
                acc[mf][nf] = MFMA16(ah[mf], bh, acc[mf][nf]);
                acc[mf][nf] = MFMA16(ah[mf], bl, acc[mf][nf]);
                acc[mf][nf] = MFMA16(al[mf], bh, acc[mf][nf]);
            }
        }
    };

    load_stage(0);
    write_stage(0);
    load_stage(32);
    __syncthreads();
    compute(0);
    write_stage(1);
    __syncthreads();
    compute(1);

#pragma unroll
    for (int nf = 0; nf < 4; nf++) {
        int col = n0 + wc * 64 + nf * 16 + (lane & 15);
#pragma unroll
        for (int mf = 0; mf < 4; mf++) {
            int rbase = m0 + wr * 64 + mf * 16 + (lane >> 4) * 4;
#pragma unroll
            for (int rr = 0; rr < 4; rr++) {
                size_t idx = (size_t)(rbase + rr) * 256 + col;
                float v = acc[mf][nf][rr];
                __bf16 hb = (__bf16)v;
                Chi[idx] = hb;
                Clo[idx] = (__bf16)(v - (float)hb);
            }
        }
    }
}

// ---------------------------------------------------------------------------
// Fused GAT layer v4: persistent block over GPB=4 graphs; 4 waves, wave owns
// 64 cols = 2 heads. Register double-buffered k-pipeline: at step ks issue
// bl(ks) + {A,bh}(ks+1), then 40 MFMAs on prefetched set, then 20 bl MFMAs.
// At ks=7 prefetch targets graph g+1 k-step 0; the attention phase (no
// global loads) covers its latency. ONE barrier per graph (WAR on h).
// Per-wave LDS (9472 B): Vhi@0 Vlo@4096 E@8192 inv@9216.
// ---------------------------------------------------------------------------
__global__ __launch_bounds__(256, 2)
void fused_gat_layer(const unsigned long long* __restrict__ masks,
                     __bf16* hhi, __bf16* hlo,
                     const __bf16* __restrict__ Whi, const __bf16* __restrict__ Wlo,
                     const float* __restrict__ bias,
                     const float* __restrict__ ba)
{
    __shared__ __align__(16) char smem[4 * 9472];

    const int tid  = threadIdx.x;
    const int lane = tid & 63;
    const int w    = tid >> 6;
    const int q    = lane >> 4;
    const int d15  = lane & 15;
    const int gbase = blockIdx.x * GPB;

    char*  wbase = smem + w * 9472;
    float* E     = (float*)(wbase + 8192);
    float* invv  = (float*)(wbase + 9216);

    // hoisted per-wave constants
    float bvv[4];
#pragma unroll
    for (int nf = 0; nf < 4; nf++) bvv[nf] = bias[w * 64 + nf * 16 + d15];
    const float bav = ba[d15];

    // fragment double buffers
    bf16x8 ah0[4], al0[4], bh0[5];
    bf16x8 ah1[4], al1[4], bh1[5];

    auto loadA = [&](bf16x8* ah, bf16x8* al, int g, int ks) {
        const int k0 = ks * 32 + q * 8;
        const size_t m0 = (size_t)g * 64;
#pragma unroll
        for (int mf = 0; mf < 4; mf++) {
            ah[mf] = *(const bf16x8*)(hhi + (m0 + mf * 16 + d15) * 256 + k0);
            al[mf] = *(const bf16x8*)(hlo + (m0 + mf * 16 + d15) * 256 + k0);
        }
    };
    auto loadBh = [&](bf16x8* bh, int ks) {
        const int k0 = ks * 32 + q * 8;
#pragma unroll
        for (int nt = 0; nt < 5; nt++) {
            int n = (nt < 4) ? (w * 64 + nt * 16 + d15) : (256 + d15);
            bh[nt] = *(const bf16x8*)(Whi + (size_t)n * 256 + k0);
        }
    };
    auto loadBl = [&](bf16x8* bl, int ks) {
        const int k0 = ks * 32 + q * 8;
#pragma unroll
        for (int nt = 0; nt < 5; nt++) {
            int n = (nt < 4) ? (w * 64 + nt * 16 + d15) : (256 + d15);
            bl[nt] = *(const bf16x8*)(Wlo + (size_t)n * 256 + k0);
        }
    };

    // prologue: graph 0, k-step 0 in flight
    loadA(ah0, al0, gbase, 0);
    loadBh(bh0, 0);

#pragma unroll 1
    for (int it = 0; it < GPB; ++it) {
        const int g = gbase + it;
        const size_t m0 = (size_t)g * 64;

        f32x4 acc[4][4], accE[4];
#pragma unroll
        for (int i = 0; i < 4; i++) {
            accE[i] = (f32x4){0.f, 0.f, 0.f, 0.f};
#pragma unroll
            for (int j = 0; j < 4; j++) acc[i][j] = (f32x4){0.f, 0.f, 0.f, 0.f};
        }

        bf16x8 bl[5];
        // MFMA helper: 40 prefetched-set MFMAs then 20 bl MFMAs
        auto mfma_block = [&](bf16x8* ah, bf16x8* al, bf16x8* bh) {
#pragma unroll
            for (int nt = 0; nt < 5; nt++) {
#pragma unroll
                for (int mf = 0; mf < 4; mf++) {
                    f32x4& dst = (nt < 4) ? acc[mf][nt] : accE[mf];
                    dst = MFMA16(ah[mf], bh[nt], dst);
                    dst = MFMA16(al[mf], bh[nt], dst);
                }
            }
#pragma unroll
            for (int nt = 0; nt < 5; nt++) {
#pragma unroll
                for (int mf = 0; mf < 4; mf++) {
                    f32x4& dst = (nt < 4) ? acc[mf][nt] : accE[mf];
                    dst = MFMA16(ah[mf], bl[nt], dst);
                }
            }
        };

#pragma unroll
        for (int ks = 0; ks < 8; ks++) {
            if ((ks & 1) == 0) {
                loadBl(bl, ks);
                if (ks < 7) { loadA(ah1, al1, g, ks + 1); loadBh(bh1, ks + 1); }
                mfma_block(ah0, al0, bh0);
            } else {
                loadBl(bl, ks);
                if (ks < 7)            { loadA(ah0, al0, g, ks + 1);  loadBh(bh0, ks + 1); }
                else if (it + 1 < GPB) { loadA(ah0, al0, g + 1, 0);   loadBh(bh0, 0); }
                mfma_block(ah1, al1, bh1);
            }
        }

        // All h A-reads of this graph complete before any epilogue h-write.
        __syncthreads();

        // adjacency masks
        unsigned long long msk[4];
#pragma unroll
        for (int mf = 0; mf < 4; mf++) msk[mf] = masks[g * 64 + mf * 16 + d15];

        // E (es/ed for this wave's heads): cols 4w..4w+3
        if (d15 >= 4 * w && d15 < 4 * w + 4) {
            const int cl = d15 - 4 * w;
#pragma unroll
            for (int mf = 0; mf < 4; mf++)
#pragma unroll
                for (int rr = 0; rr < 4; rr++)
                    E[cl * 64 + mf * 16 + q * 4 + rr] = accE[mf][rr] + bav;
        }

        // per-head: V frags -> in-register P synth -> PV MFMA -> store
#pragma unroll
        for (int hl = 0; hl < 2; hl++) {
            const int head = 2 * w + hl;

#pragma unroll
            for (int nfl = 0; nfl < 2; nfl++) {
                const int nf = hl * 2 + nfl;
                const int d  = nfl * 16 + d15;
                const float bv = bvv[nf];
                char* vb = wbase + d * 128;
#pragma unroll
                for (int mf = 0; mf < 4; mf++) {
                    int s   = mf * 2 + (q >> 1);
                    int off = ((s ^ (d & 7)) << 4) + (q & 1) * 8;
                    bf16x4 h4, l4;
#pragma unroll
                    for (int rr = 0; rr < 4; rr++) {
                        float v = acc[mf][nf][rr] + bv;
                        __bf16 hb = (__bf16)v;
                        h4[rr] = hb;
                        l4[rr] = (__bf16)(v - (float)hb);
                    }
                    *(bf16x4*)(vb + off)        = h4;
                    *(bf16x4*)(vb + 4096 + off) = l4;
                }
            }

            float ev = E[(hl * 2 + 1) * 64 + lane];
#pragma unroll
            for (int off = 32; off; off >>= 1) ev = fmaxf(ev, __shfl_xor(ev, off));

            float esi[4], mh[4];
#pragma unroll
            for (int mf = 0; mf < 4; mf++) {
                esi[mf] = E[(hl * 2) * 64 + mf * 16 + d15];
                mh[mf]  = leaky(esi[mf] + ev);
            }

            f32x4 pv[4][2];
#pragma unroll
            for (int mf = 0; mf < 4; mf++) {
                pv[mf][0] = (f32x4){0.f, 0.f, 0.f, 0.f};
                pv[mf][1] = (f32x4){0.f, 0.f, 0.f, 0.f};
            }
            float rs[4] = {0.f, 0.f, 0.f, 0.f};

#pragma unroll
            for (int ksj = 0; ksj < 2; ksj++) {
                const int j8 = ksj * 32 + q * 8;
                const int s  = ksj * 4 + q;
                bf16x8 vh[2], vl[2];
#pragma unroll
                for (int nf2 = 0; nf2 < 2; nf2++) {
                    int d = nf2 * 16 + d15;
                    int off = d * 128 + ((s ^ (d & 7)) << 4);
                    vh[nf2] = *(const bf16x8*)(wbase + off);
                    vl[nf2] = *(const bf16x8*)(wbase + 4096 + off);
                }
                float edv[8];
#pragma unroll
                for (int e = 0; e < 8; e++) edv[e] = E[(hl * 2 + 1) * 64 + j8 + e];

#pragma unroll
                for (int mf = 0; mf < 4; mf++) {
                    unsigned int mb = (unsigned int)(msk[mf] >> j8) & 0xffu;
                    bf16x8 ph, pl;
                    float rsum = 0.f;
#pragma unroll
                    for (int e = 0; e < 8; e++) {
                        float t = leaky(esi[mf] + edv[e]);
                        float p = ((mb >> e) & 1u) ? __expf(t - mh[mf]) : 0.f;
                        rsum += p;
                        __bf16 hb = (__bf16)p;
                        ph[e] = hb;
                        pl[e] = (__bf16)(p - (float)hb);
                    }
                    rs[mf] += rsum;
#pragma unroll
                    for (int nf2 = 0; nf2 < 2; nf2++) {
                        pv[mf][nf2] = MFMA16(ph, vh[nf2], pv[mf][nf2]);
                        pv[mf][nf2] = MFMA16(ph, vl[nf2], pv[mf][nf2]);
                        pv[mf][nf2] = MFMA16(pl, vh[nf2], pv[mf][nf2]);
                    }
                }
            }

            // row sums -> 1/s
#pragma unroll
            for (int mf = 0; mf < 4; mf++) {
                float r = rs[mf];
                r += __shfl_xor(r, 16);
                r += __shfl_xor(r, 32);
                if (q == 0) invv[mf * 16 + d15] = (r > 0.f) ? 1.f / r : 0.f;
            }

            // epilogue: scale, residual (hi+lo), ELU, re-split store
#pragma unroll
            for (int mf = 0; mf < 4; mf++) {
#pragma unroll
                for (int nf2 = 0; nf2 < 2; nf2++) {
                    int d = head * 32 + nf2 * 16 + d15;
#pragma unroll
                    for (int rr = 0; rr < 4; rr++) {
                        int i = mf * 16 + q * 4 + rr;
                        float inv = invv[i];
                        size_t idx = (m0 + i) * 256 + d;
                        float old = (float)hhi[idx] + (float)hlo[idx];
                        float o = pv[mf][nf2][rr] * inv + old;
                        o = o > 0.f ? o : __expf(o) - 1.f;
                        __bf16 hb = (__bf16)o;
                        hhi[idx] = hb;
                        hlo[idx] = (__bf16)(o - (float)hb);
                    }
                }
            }
        }
    }
}

// ---------------------------------------------------------------------------
// Masked mean-pool + 3-layer MLP + elu + 1.5. One block per graph.
// ---------------------------------------------------------------------------
__global__ __launch_bounds__(256)
void pool_mlp(const unsigned long long* __restrict__ masks,
              const __bf16* __restrict__ hhi, const __bf16* __restrict__ hlo,
              const float* __restrict__ W1, const float* __restrict__ b1,
              const float* __restrict__ W2, const float* __restrict__ b2,
              const float* __restrict__ W3, const float* __restrict__ b3,
              float* __restrict__ out)
{
    __shared__ float lds_g[256];
    __shared__ float lds_z1[128];
    __shared__ float lds_z2[128];
    __shared__ unsigned long long lds_m;
    __shared__ float lds_invcnt;

    const int tid = threadIdx.x;
    const int b   = blockIdx.x;
    const __bf16* hbh = hhi + (size_t)b * 16384;
    const __bf16* hbl = hlo + (size_t)b * 16384;

    if (tid < 64) {
        unsigned long long rowm = masks[b * 64 + tid];
        unsigned long long m = __ballot((rowm >> tid) & 1ULL);
        if (tid == 0) { lds_m = m; lds_invcnt = 1.f / (float)__popcll(m); }
    }
    __syncthreads();

    unsigned long long msk = lds_m;
    float invc = lds_invcnt;
    float gsum = 0.f;
    for (int n = 0; n < 64; n++)
        if ((msk >> n) & 1ULL)
            gsum += (float)hbh[n * 256 + tid] + (float)hbl[n * 256 + tid];
    lds_g[tid] = gsum * invc;
    __syncthreads();

    if (tid < 128) {
        const float* wr = W1 + tid * 256;
        float z = 0.f;
#pragma unroll 8
        for (int k = 0; k < 256; k += 4) {
            float4 wv = *(const float4*)&wr[k];
            z += wv.x * lds_g[k] + wv.y * lds_g[k + 1] + wv.z * lds_g[k + 2] + wv.w * lds_g[k + 3];
        }
        z += b1[tid];
        lds_z1[tid] = z > 0.f ? z : 0.f;
    }
    __syncthreads();

    if (tid < 128) {
        const float* wr = W2 + tid * 128;
        float z = 0.f;
#pragma unroll 8
        for (int k = 0; k < 128; k += 4) {
            float4 wv = *(const float4*)&wr[k];
            z += wv.x * lds_z1[k] + wv.y * lds_z1[k + 1] + wv.z * lds_z1[k + 2] + wv.w * lds_z1[k + 3];
        }
        z += b2[tid];
        lds_z2[tid] = z > 0.f ? z : 0.f;
    }
    __syncthreads();

    if (tid < 64) {
        float p = W3[tid] * lds_z2[tid] + W3[tid + 64] * lds_z2[tid + 64];
        for (int off = 32; off; off >>= 1) p += __shfl_down(p, off);
        if (tid == 0) {
            float z = p + b3[0];
            out[b] = (z > 0.f ? z : __expf(z) - 1.f) + 1.5f;
        }
    }
}

// ---------------------------------------------------------------------------
extern "C" void kernel_launch(void* const* d_in, const int* in_sizes, int n_in,
                              void* d_out, int out_size, void* d_ws, size_t ws_size,
                              hipStream_t stream)
{
    const float* x      = (const float*)d_in[0];
    const float* A      = (const float*)d_in[1];
    const float* W_emb  = (const float*)d_in[2];
    const float* gat_W  = (const float*)d_in[3];
    const float* gat_b  = (const float*)d_in[4];
    const float* gat_a  = (const float*)d_in[5];
    const float* fc_W1  = (const float*)d_in[6];
    const float* fc_b1  = (const float*)d_in[7];
    const float* fc_W2  = (const float*)d_in[8];
    const float* fc_b2  = (const float*)d_in[9];
    const float* fc_W3  = (const float*)d_in[10];
    const float* fc_b3  = (const float*)d_in[11];
    float* out = (float*)d_out;

    // workspace (~171 MB):
    //   hhi bf16 [131072][256]      @ 0            67108864
    //   hlo bf16 [131072][256]      @ 67108864     67108864
    //   xhi/xlo bf16 [131072][64]   @ 134217728    2 x 16777216
    //   Whi_emb/Wlo_emb [256][64]   @ 167772160    2 x 32768
    //   Whi [6][272][256] bf16      @ 167837696    835584
    //   Wlo                         @ 168673280    835584
    //   ba  [6][16] f32             @ 169508864    384
    //   masks u64 [2048][64]        @ 169510912    1048576
    char* ws = (char*)d_ws;
    __bf16* hhi     = (__bf16*)ws;
    __bf16* hlo     = (__bf16*)(ws + 67108864);
    __bf16* xhi     = (__bf16*)(ws + 134217728);
    __bf16* xlo     = (__bf16*)(ws + 134217728 + 16777216);
    __bf16* Whi_emb = (__bf16*)(ws + 167772160);
    __bf16* Wlo_emb = (__bf16*)(ws + 167772160 + 32768);
    __bf16* Whi     = (__bf16*)(ws + 167837696);
    __bf16* Wlo     = (__bf16*)(ws + 168673280);
    float*  ba      = (float*)(ws + 169508864);
    unsigned long long* masks = (unsigned long long*)(ws + 169510912);

    int conv_total = L_LAYERS * 65536 + L_LAYERS * 4096 + L_LAYERS * 16;
    convert_weights<<<(conv_total + 255) / 256, 256, 0, stream>>>(
        W_emb, gat_W, gat_a, gat_b, Whi_emb, Wlo_emb, Whi, Wlo, ba);
    convert_x<<<M_FULL * 64 / 256, 256, 0, stream>>>(x, xhi, xlo);
    build_masks<<<B_GRAPHS, 256, 0, stream>>>(A, masks);

    gemm_embed<<<dim3(M_FULL / 128, 2), 256, 0, stream>>>(
        xhi, xlo, Whi_emb, Wlo_emb, hhi, hlo);

    for (int l = 0; l < L_LAYERS; l++) {
        fused_gat_layer<<<B_GRAPHS / GPB, 256, 0, stream>>>(
            masks, hhi, hlo,
            Whi + (size_t)l * WSLAB, Wlo + (size_t)l * WSLAB,
            gat_b + l * D_DIM, ba + l * 16);
    }

    pool_mlp<<<B_GRAPHS, 256, 0, stream>>>(masks, hhi, hlo, fc_W1, fc_b1,
                                           fc_W2, fc_b2, fc_W3, fc_b3, out);
}

// Round 9
// 820.276 us; speedup vs baseline: 3.7881x; 3.7881x over previous
//
#include <hip/hip_runtime.h>
#include <cstdint>
#include <cstddef>

#define B_GRAPHS 2048
#define N_NODES  64
#define FIN      49
#define D_DIM    256
#define H_HEADS  8
#define DK_DIM   32
#define L_LAYERS 6
#define ALPHA    0.2f

#define M_FULL     (B_GRAPHS * N_NODES)           // 131072 rows
#define WROWS      272                             // 256 W rows + 16 Wa rows
#define WSLAB      (WROWS * 256)                   // per-layer weight slab elems

typedef __bf16 bf16x8 __attribute__((ext_vector_type(8)));
typedef __bf16 bf16x4 __attribute__((ext_vector_type(4)));
typedef float  f32x4  __attribute__((ext_vector_type(4)));

#define MFMA16(a, b, c) __builtin_amdgcn_mfma_f32_16x16x32_bf16(a, b, c, 0, 0, 0)

__device__ __forceinline__ float leaky(float t) { return t > 0.f ? t : ALPHA * t; }

// ---------------------------------------------------------------------------
// Weight prep: W (+ appended Wa = W^T a rows) to single bf16; ba = b.a (f32).
//   Wb: [6][272][256]; rows 0..255 = W[n][k], rows 256..271 = Wa[c][k].
// ---------------------------------------------------------------------------
__global__ void convert_weights(const float* __restrict__ W_emb,
                                const float* __restrict__ gat_W,
                                const float* __restrict__ gat_a,
                                const float* __restrict__ gat_b,
                                __bf16* __restrict__ Wemb_b,   // [256][64]
                                __bf16* __restrict__ Wb,       // [6][272][256]
                                float* __restrict__ ba)        // [6][16]
{
    int idx = blockIdx.x * 256 + threadIdx.x;
    if (idx < 256 * 64) {
        int n = idx >> 6, k = idx & 63;
        float f = (k < FIN) ? W_emb[n * FIN + k] : 0.f;
        Wemb_b[idx] = (__bf16)f;
    }
    if (idx < L_LAYERS * 65536) {
        int l = idx >> 16, nk = idx & 65535;
        Wb[l * WSLAB + nk] = (__bf16)gat_W[idx];
    }
    int o = idx - L_LAYERS * 65536;
    if (o >= 0 && o < L_LAYERS * 4096) {
        int l = o >> 12, r = o & 4095;
        int k = r >> 4, c = r & 15;
        int hh = c >> 1, sd = c & 1;
        const float* av = gat_a + l * 512 + hh * 64 + sd * 32;
        const float* wp = gat_W + ((size_t)l * 256 + hh * 32) * 256 + k;
        float s = 0.f;
        for (int d = 0; d < 32; d++) s += av[d] * wp[d * 256];
        Wb[l * WSLAB + (256 + c) * 256 + k] = (__bf16)s;
    }
    int o2 = idx - L_LAYERS * 65536 - L_LAYERS * 4096;
    if (o2 >= 0 && o2 < L_LAYERS * 16) {
        int l = o2 >> 4, c = o2 & 15;
        int hh = c >> 1, sd = c & 1;
        const float* av = gat_a + l * 512 + hh * 64 + sd * 32;
        const float* bp = gat_b + l * 256 + hh * 32;
        float s = 0.f;
        for (int d = 0; d < 32; d++) s += av[d] * bp[d];
        ba[o2] = s;
    }
}

// x [M][49] fp32 -> xb [M][64] bf16 (zero-padded)
__global__ void convert_x(const float* __restrict__ x, __bf16* __restrict__ xb)
{
    int idx = blockIdx.x * 256 + threadIdx.x;
    int m = idx >> 6, k = idx & 63;
    xb[idx] = (__bf16)((k < FIN) ? x[m * FIN + k] : 0.f);
}

// ---------------------------------------------------------------------------
// Adjacency bitmasks, once: masks[g][r] bit j = A[g][r][j] > 0.
// ---------------------------------------------------------------------------
__global__ void build_masks(const float* __restrict__ A,
                            unsigned long long* __restrict__ masks)
{
    int g = blockIdx.x;
    int lane = threadIdx.x & 63;
    int w = threadIdx.x >> 6;
    const float* Ab = A + (size_t)g * 4096;
    for (int rr = 0; rr < 16; rr++) {
        int r = w * 16 + rr;
        unsigned long long m = __ballot(Ab[r * 64 + lane] > 0.f);
        if (lane == 0) masks[g * 64 + r] = m;
    }
}

// ---------------------------------------------------------------------------
// Embed GEMM: h[M,256] = bf16(x @ W_emb^T).  1-term bf16 MFMA, fp32 acc.
// ---------------------------------------------------------------------------
__device__ __forceinline__ int swz(int r, int s) {
    return r * 64 + (((s ^ (r & 3)) << 4));
}

__global__ __launch_bounds__(256, 2)
void gemm_embed(const __bf16* __restrict__ Ab, const __bf16* __restrict__ Bb,
                __bf16* __restrict__ C)
{
    const int K = 64;
    __shared__ __align__(16) char lds[2][16384];   // A@0 (8K), B@8192 (8K)

    const int tid  = threadIdx.x;
    const int m0   = blockIdx.x * 128;
    const int n0   = blockIdx.y * 128;
    const int lane = tid & 63;
    const int wid  = tid >> 6;
    const int wr   = wid >> 1, wc = wid & 1;

    bf16x8 regA[2], regB[2];
    f32x4 acc[4][4];
#pragma unroll
    for (int i = 0; i < 4; i++)
#pragma unroll
        for (int j = 0; j < 4; j++) acc[i][j] = (f32x4){0.f, 0.f, 0.f, 0.f};

    auto load_stage = [&](int k0) {
#pragma unroll
        for (int g = 0; g < 2; g++) {
            int u = g * 256 + tid, r = u >> 2, s = u & 3;
            regA[g] = *(const bf16x8*)(Ab + (size_t)(m0 + r) * K + k0 + s * 8);
            regB[g] = *(const bf16x8*)(Bb + (size_t)(n0 + r) * K + k0 + s * 8);
        }
    };
    auto write_stage = [&](int buf) {
        char* base = lds[buf];
#pragma unroll
        for (int g = 0; g < 2; g++) {
            int u = g * 256 + tid, r = u >> 2, s = u & 3;
            int off = swz(r, s);
            *(bf16x8*)(base + off)        = regA[g];
            *(bf16x8*)(base + 8192 + off) = regB[g];
        }
    };
    auto compute = [&](int buf) {
        const char* base = lds[buf];
        const int s = lane >> 4;
        bf16x8 ah[4];
#pragma unroll
        for (int mf = 0; mf < 4; mf++)
            ah[mf] = *(const bf16x8*)(base + swz(wr * 64 + mf * 16 + (lane & 15), s));
#pragma unroll
        for (int nf = 0; nf < 4; nf++) {
            bf16x8 bh = *(const bf16x8*)(base + 8192 +
                            swz(wc * 64 + nf * 16 + (lane & 15), s));
#pragma unroll
            for (int mf = 0; mf < 4; mf++)
                acc[mf][nf] = MFMA16(ah[mf], bh, acc[mf][nf]);
        }
    };

    load_stage(0);
    write_stage(0);
    load_stage(32);
    __syncthreads();
    compute(0);
    write_stage(1);
    __syncthreads();
    compute(1);

#pragma unroll
    for (int nf = 0; nf < 4; nf++) {
        int col = n0 + wc * 64 + nf * 16 + (lane & 15);
#pragma unroll
        for (int mf = 0; mf < 4; mf++) {
            int rbase = m0 + wr * 64 + mf * 16 + (lane >> 4) * 4;
#pragma unroll
            for (int rr = 0; rr < 4; rr++)
                C[(size_t)(rbase + rr) * 256 + col] = (__bf16)acc[mf][nf][rr];
        }
    }
}

// ---------------------------------------------------------------------------
// Fused GAT layer v5 (plain bf16 forward, fp32 accum): one graph/block,
// 4 waves, wave owns 64 cols = 2 heads sequentially. 1-term MFMA everywhere.
// Per-wave LDS (5376 B): V@0 (4K) E@4096 (1K) inv@5120 (256).
// ONE barrier (WAR: all h A-reads before any epilogue h-write).
// NOTE: keep __launch_bounds__(256,2) — (256,4) caused spill (R6); full
// register double-buffering caused spill (R8). Do not reintroduce either.
// ---------------------------------------------------------------------------
__global__ __launch_bounds__(256, 2)
void fused_gat_layer(const unsigned long long* __restrict__ masks,
                     __bf16* h,
                     const __bf16* __restrict__ Wb,
                     const float* __restrict__ bias,
                     const float* __restrict__ ba)
{
    __shared__ __align__(16) char smem[4 * 5376];

    const int tid  = threadIdx.x;
    const int lane = tid & 63;
    const int w    = tid >> 6;
    const int q    = lane >> 4;
    const int d15  = lane & 15;
    const int g    = blockIdx.x;
    const size_t m0 = (size_t)g * 64;

    char*  wbase = smem + w * 5376;
    float* E     = (float*)(wbase + 4096);
    float* invv  = (float*)(wbase + 5120);

    // hoisted constants
    float bvv[4];
#pragma unroll
    for (int nf = 0; nf < 4; nf++) bvv[nf] = bias[w * 64 + nf * 16 + d15];
    const float bav = ba[d15];

    // --- GEMM: acc[mf][nf] = hp tile (wave's 64 cols), accE = es/ed tile ---
    f32x4 acc[4][4], accE[4];
#pragma unroll
    for (int i = 0; i < 4; i++) {
        accE[i] = (f32x4){0.f, 0.f, 0.f, 0.f};
#pragma unroll
        for (int j = 0; j < 4; j++) acc[i][j] = (f32x4){0.f, 0.f, 0.f, 0.f};
    }

#pragma unroll 2
    for (int ks = 0; ks < 8; ks++) {
        const int k0 = ks * 32 + q * 8;
        bf16x8 ah[4];
#pragma unroll
        for (int mf = 0; mf < 4; mf++)
            ah[mf] = *(const bf16x8*)(h + (m0 + mf * 16 + d15) * 256 + k0);
#pragma unroll
        for (int nt = 0; nt < 5; nt++) {
            int n = (nt < 4) ? (w * 64 + nt * 16 + d15) : (256 + d15);
            bf16x8 bh = *(const bf16x8*)(Wb + (size_t)n * 256 + k0);
#pragma unroll
            for (int mf = 0; mf < 4; mf++) {
                f32x4& dst = (nt < 4) ? acc[mf][nt] : accE[mf];
                dst = MFMA16(ah[mf], bh, dst);
            }
        }
    }

    // All h A-reads complete before any epilogue h-write (only barrier).
    __syncthreads();

    // adjacency masks
    unsigned long long msk[4];
#pragma unroll
    for (int mf = 0; mf < 4; mf++) msk[mf] = masks[g * 64 + mf * 16 + d15];

    // E (es/ed for this wave's heads): cols 4w..4w+3
    if (d15 >= 4 * w && d15 < 4 * w + 4) {
        const int cl = d15 - 4 * w;
#pragma unroll
        for (int mf = 0; mf < 4; mf++)
#pragma unroll
            for (int rr = 0; rr < 4; rr++)
                E[cl * 64 + mf * 16 + q * 4 + rr] = accE[mf][rr] + bav;
    }

    // --- per-head: V frags -> in-register P synth -> PV MFMA -> store ---
#pragma unroll
    for (int hl = 0; hl < 2; hl++) {
        const int head = 2 * w + hl;

        // V fragments for this head (wave-private, swizzled [d][j] bf16)
#pragma unroll
        for (int nfl = 0; nfl < 2; nfl++) {
            const int nf = hl * 2 + nfl;
            const int d  = nfl * 16 + d15;
            const float bv = bvv[nf];
            char* vb = wbase + d * 128;
#pragma unroll
            for (int mf = 0; mf < 4; mf++) {
                int s   = mf * 2 + (q >> 1);
                int off = ((s ^ (d & 7)) << 4) + (q & 1) * 8;
                bf16x4 h4;
#pragma unroll
                for (int rr = 0; rr < 4; rr++)
                    h4[rr] = (__bf16)(acc[mf][nf][rr] + bv);
                *(bf16x4*)(vb + off) = h4;
            }
        }

        float ev = E[(hl * 2 + 1) * 64 + lane];
#pragma unroll
        for (int off = 32; off; off >>= 1) ev = fmaxf(ev, __shfl_xor(ev, off));

        float esi[4], mh[4];
#pragma unroll
        for (int mf = 0; mf < 4; mf++) {
            esi[mf] = E[(hl * 2) * 64 + mf * 16 + d15];
            mh[mf]  = leaky(esi[mf] + ev);
        }

        f32x4 pv[4][2];
#pragma unroll
        for (int mf = 0; mf < 4; mf++) {
            pv[mf][0] = (f32x4){0.f, 0.f, 0.f, 0.f};
            pv[mf][1] = (f32x4){0.f, 0.f, 0.f, 0.f};
        }
        float rs[4] = {0.f, 0.f, 0.f, 0.f};

#pragma unroll
        for (int ksj = 0; ksj < 2; ksj++) {
            const int j8 = ksj * 32 + q * 8;
            const int s  = ksj * 4 + q;
            bf16x8 vh[2];
#pragma unroll
            for (int nf2 = 0; nf2 < 2; nf2++) {
                int d = nf2 * 16 + d15;
                vh[nf2] = *(const bf16x8*)(wbase + d * 128 + ((s ^ (d & 7)) << 4));
            }
            float edv[8];
#pragma unroll
            for (int e = 0; e < 8; e++) edv[e] = E[(hl * 2 + 1) * 64 + j8 + e];

#pragma unroll
            for (int mf = 0; mf < 4; mf++) {
                unsigned int mb = (unsigned int)(msk[mf] >> j8) & 0xffu;
                bf16x8 ph;
                float rsum = 0.f;
#pragma unroll
                for (int e = 0; e < 8; e++) {
                    float t = leaky(esi[mf] + edv[e]);
                    float p = ((mb >> e) & 1u) ? __expf(t - mh[mf]) : 0.f;
                    rsum += p;
                    ph[e] = (__bf16)p;
                }
                rs[mf] += rsum;
#pragma unroll
                for (int nf2 = 0; nf2 < 2; nf2++)
                    pv[mf][nf2] = MFMA16(ph, vh[nf2], pv[mf][nf2]);
            }
        }

        // row sums -> 1/s
#pragma unroll
        for (int mf = 0; mf < 4; mf++) {
            float r = rs[mf];
            r += __shfl_xor(r, 16);
            r += __shfl_xor(r, 32);
            if (q == 0) invv[mf * 16 + d15] = (r > 0.f) ? 1.f / r : 0.f;
        }

        // epilogue: scale, residual, ELU, bf16 store (wave-own cols only)
#pragma unroll
        for (int mf = 0; mf < 4; mf++) {
#pragma unroll
            for (int nf2 = 0; nf2 < 2; nf2++) {
                int d = head * 32 + nf2 * 16 + d15;
#pragma unroll
                for (int rr = 0; rr < 4; rr++) {
                    int i = mf * 16 + q * 4 + rr;
                    float inv = invv[i];
                    size_t idx = (m0 + i) * 256 + d;
                    float o = pv[mf][nf2][rr] * inv + (float)h[idx];
                    o = o > 0.f ? o : __expf(o) - 1.f;
                    h[idx] = (__bf16)o;
                }
            }
        }
    }
}

// ---------------------------------------------------------------------------
// Masked mean-pool + 3-layer MLP + elu + 1.5. One block per graph.
// ---------------------------------------------------------------------------
__global__ __launch_bounds__(256)
void pool_mlp(const unsigned long long* __restrict__ masks,
              const __bf16* __restrict__ h,
              const float* __restrict__ W1, const float* __restrict__ b1,
              const float* __restrict__ W2, const float* __restrict__ b2,
              const float* __restrict__ W3, const float* __restrict__ b3,
              float* __restrict__ out)
{
    __shared__ float lds_g[256];
    __shared__ float lds_z1[128];
    __shared__ float lds_z2[128];
    __shared__ unsigned long long lds_m;
    __shared__ float lds_invcnt;

    const int tid = threadIdx.x;
    const int b   = blockIdx.x;
    const __bf16* hb = h + (size_t)b * 16384;

    if (tid < 64) {
        unsigned long long rowm = masks[b * 64 + tid];
        unsigned long long m = __ballot((rowm >> tid) & 1ULL);
        if (tid == 0) { lds_m = m; lds_invcnt = 1.f / (float)__popcll(m); }
    }
    __syncthreads();

    unsigned long long msk = lds_m;
    float invc = lds_invcnt;
    float gsum = 0.f;
    for (int n = 0; n < 64; n++)
        if ((msk >> n) & 1ULL) gsum += (float)hb[n * 256 + tid];
    lds_g[tid] = gsum * invc;
    __syncthreads();

    if (tid < 128) {
        const float* wr = W1 + tid * 256;
        float z = 0.f;
#pragma unroll 8
        for (int k = 0; k < 256; k += 4) {
            float4 wv = *(const float4*)&wr[k];
            z += wv.x * lds_g[k] + wv.y * lds_g[k + 1] + wv.z * lds_g[k + 2] + wv.w * lds_g[k + 3];
        }
        z += b1[tid];
        lds_z1[tid] = z > 0.f ? z : 0.f;
    }
    __syncthreads();

    if (tid < 128) {
        const float* wr = W2 + tid * 128;
        float z = 0.f;
#pragma unroll 8
        for (int k = 0; k < 128; k += 4) {
            float4 wv = *(const float4*)&wr[k];
            z += wv.x * lds_z1[k] + wv.y * lds_z1[k + 1] + wv.z * lds_z1[k + 2] + wv.w * lds_z1[k + 3];
        }
        z += b2[tid];
        lds_z2[tid] = z > 0.f ? z : 0.f;
    }
    __syncthreads();

    if (tid < 64) {
        float p = W3[tid] * lds_z2[tid] + W3[tid + 64] * lds_z2[tid + 64];
        for (int off = 32; off; off >>= 1) p += __shfl_down(p, off);
        if (tid == 0) {
            float z = p + b3[0];
            out[b] = (z > 0.f ? z : __expf(z) - 1.f) + 1.5f;
        }
    }
}

// ---------------------------------------------------------------------------
extern "C" void kernel_launch(void* const* d_in, const int* in_sizes, int n_in,
                              void* d_out, int out_size, void* d_ws, size_t ws_size,
                              hipStream_t stream)
{
    const float* x      = (const float*)d_in[0];
    const float* A      = (const float*)d_in[1];
    const float* W_emb  = (const float*)d_in[2];
    const float* gat_W  = (const float*)d_in[3];
    const float* gat_b  = (const float*)d_in[4];
    const float* gat_a  = (const float*)d_in[5];
    const float* fc_W1  = (const float*)d_in[6];
    const float* fc_b1  = (const float*)d_in[7];
    const float* fc_W2  = (const float*)d_in[8];
    const float* fc_b2  = (const float*)d_in[9];
    const float* fc_W3  = (const float*)d_in[10];
    const float* fc_b3  = (const float*)d_in[11];
    float* out = (float*)d_out;

    // workspace (~86 MB):
    //   h  bf16 [131072][256]   @ 0          67108864
    //   xb bf16 [131072][64]    @ 67108864   16777216
    //   Wemb_b [256][64]        @ 83886080   32768
    //   Wb [6][272][256] bf16   @ 83918848   835584
    //   ba [6][16] f32          @ 84754432   384
    //   masks u64 [2048][64]    @ 84754816   1048576
    char* ws = (char*)d_ws;
    __bf16* h      = (__bf16*)ws;
    __bf16* xb     = (__bf16*)(ws + 67108864);
    __bf16* Wemb_b = (__bf16*)(ws + 83886080);
    __bf16* Wb     = (__bf16*)(ws + 83918848);
    float*  ba     = (float*)(ws + 84754432);
    unsigned long long* masks = (unsigned long long*)(ws + 84754816);

    int conv_total = L_LAYERS * 65536 + L_LAYERS * 4096 + L_LAYERS * 16;
    convert_weights<<<(conv_total + 255) / 256, 256, 0, stream>>>(
        W_emb, gat_W, gat_a, gat_b, Wemb_b, Wb, ba);
    convert_x<<<M_FULL * 64 / 256, 256, 0, stream>>>(x, xb);
    build_masks<<<B_GRAPHS, 256, 0, stream>>>(A, masks);

    gemm_embed<<<dim3(M_FULL / 128, 2), 256, 0, stream>>>(xb, Wemb_b, h);

    for (int l = 0; l < L_LAYERS; l++) {
        fused_gat_layer<<<B_GRAPHS, 256, 0, stream>>>(
            masks, h,
            Wb + (size_t)l * WSLAB,
            gat_b + l * D_DIM, ba + l * 16);
    }

    pool_mlp<<<B_GRAPHS, 256, 0, stream>>>(masks, h, fc_W1, fc_b1,
                                           fc_W2, fc_b2, fc_W3, fc_b3, out);
}

// Round 10
// 818.837 us; speedup vs baseline: 3.7947x; 1.0018x over previous
//
#include <hip/hip_runtime.h>
#include <cstdint>
#include <cstddef>

#define B_GRAPHS 2048
#define N_NODES  64
#define FIN      49
#define D_DIM    256
#define H_HEADS  8
#define DK_DIM   32
#define L_LAYERS 6
#define ALPHA    0.2f
#define LOG2E    1.4426950408889634f

#define M_FULL     (B_GRAPHS * N_NODES)           // 131072 rows
#define WSLAB      (256 * 256)                     // per-layer weight slab elems

typedef __bf16 bf16x8 __attribute__((ext_vector_type(8)));
typedef __bf16 bf16x4 __attribute__((ext_vector_type(4)));
typedef float  f32x4  __attribute__((ext_vector_type(4)));

#define MFMA16(a, b, c) __builtin_amdgcn_mfma_f32_16x16x32_bf16(a, b, c, 0, 0, 0)

__device__ __forceinline__ float leaky(float t) { return t > 0.f ? t : ALPHA * t; }

// ---------------------------------------------------------------------------
// Weight prep: W -> single bf16; ba[l][c] = a[l,h,sd*32:] . b[l,h*32:] (f32).
// ---------------------------------------------------------------------------
__global__ void convert_weights(const float* __restrict__ W_emb,
                                const float* __restrict__ gat_W,
                                const float* __restrict__ gat_a,
                                const float* __restrict__ gat_b,
                                __bf16* __restrict__ Wemb_b,   // [256][64]
                                __bf16* __restrict__ Wb,       // [6][256][256]
                                float* __restrict__ ba)        // [6][16]
{
    int idx = blockIdx.x * 256 + threadIdx.x;
    if (idx < 256 * 64) {
        int n = idx >> 6, k = idx & 63;
        float f = (k < FIN) ? W_emb[n * FIN + k] : 0.f;
        Wemb_b[idx] = (__bf16)f;
    }
    if (idx < L_LAYERS * 65536) {
        Wb[idx] = (__bf16)gat_W[idx];
    }
    int o2 = idx - L_LAYERS * 65536;
    if (o2 >= 0 && o2 < L_LAYERS * 16) {
        int l = o2 >> 4, c = o2 & 15;
        int hh = c >> 1, sd = c & 1;
        const float* av = gat_a + l * 512 + hh * 64 + sd * 32;
        const float* bp = gat_b + l * 256 + hh * 32;
        float s = 0.f;
        for (int d = 0; d < 32; d++) s += av[d] * bp[d];
        ba[o2] = s;
    }
}

// x [M][49] fp32 -> xb [M][64] bf16 (zero-padded)
__global__ void convert_x(const float* __restrict__ x, __bf16* __restrict__ xb)
{
    int idx = blockIdx.x * 256 + threadIdx.x;
    int m = idx >> 6, k = idx & 63;
    xb[idx] = (__bf16)((k < FIN) ? x[m * FIN + k] : 0.f);
}

// ---------------------------------------------------------------------------
// Adjacency bitmasks, once: masks[g][r] bit j = A[g][r][j] > 0.
// ---------------------------------------------------------------------------
__global__ void build_masks(const float* __restrict__ A,
                            unsigned long long* __restrict__ masks)
{
    int g = blockIdx.x;
    int lane = threadIdx.x & 63;
    int w = threadIdx.x >> 6;
    const float* Ab = A + (size_t)g * 4096;
    for (int rr = 0; rr < 16; rr++) {
        int r = w * 16 + rr;
        unsigned long long m = __ballot(Ab[r * 64 + lane] > 0.f);
        if (lane == 0) masks[g * 64 + r] = m;
    }
}

// ---------------------------------------------------------------------------
// Embed GEMM: h[M,256] = bf16(x @ W_emb^T).  bf16 MFMA, fp32 acc.
// ---------------------------------------------------------------------------
__device__ __forceinline__ int swz(int r, int s) {
    return r * 64 + (((s ^ (r & 3)) << 4));
}

__global__ __launch_bounds__(256, 2)
void gemm_embed(const __bf16* __restrict__ Ab, const __bf16* __restrict__ Bb,
                __bf16* __restrict__ C)
{
    const int K = 64;
    __shared__ __align__(16) char lds[2][16384];   // A@0 (8K), B@8192 (8K)

    const int tid  = threadIdx.x;
    const int m0   = blockIdx.x * 128;
    const int n0   = blockIdx.y * 128;
    const int lane = tid & 63;
    const int wid  = tid >> 6;
    const int wr   = wid >> 1, wc = wid & 1;

    bf16x8 regA[2], regB[2];
    f32x4 acc[4][4];
#pragma unroll
    for (int i = 0; i < 4; i++)
#pragma unroll
        for (int j = 0; j < 4; j++) acc[i][j] = (f32x4){0.f, 0.f, 0.f, 0.f};

    auto load_stage = [&](int k0) {
#pragma unroll
        for (int g = 0; g < 2; g++) {
            int u = g * 256 + tid, r = u >> 2, s = u & 3;
            regA[g] = *(const bf16x8*)(Ab + (size_t)(m0 + r) * K + k0 + s * 8);
            regB[g] = *(const bf16x8*)(Bb + (size_t)(n0 + r) * K + k0 + s * 8);
        }
    };
    auto write_stage = [&](int buf) {
        char* base = lds[buf];
#pragma unroll
        for (int g = 0; g < 2; g++) {
            int u = g * 256 + tid, r = u >> 2, s = u & 3;
            int off = swz(r, s);
            *(bf16x8*)(base + off)        = regA[g];
            *(bf16x8*)(base + 8192 + off) = regB[g];
        }
    };
    auto compute = [&](int buf) {
        const char* base = lds[buf];
        const int s = lane >> 4;
        bf16x8 ah[4];
#pragma unroll
        for (int mf = 0; mf < 4; mf++)
            ah[mf] = *(const bf16x8*)(base + swz(wr * 64 + mf * 16 + (lane & 15), s));
#pragma unroll
        for (int nf = 0; nf < 4; nf++) {
            bf16x8 bh = *(const bf16x8*)(base + 8192 +
                            swz(wc * 64 + nf * 16 + (lane & 15), s));
#pragma unroll
            for (int mf = 0; mf < 4; mf++)
                acc[mf][nf] = MFMA16(ah[mf], bh, acc[mf][nf]);
        }
    };

    load_stage(0);
    write_stage(0);
    load_stage(32);
    __syncthreads();
    compute(0);
    write_stage(1);
    __syncthreads();
    compute(1);

#pragma unroll
    for (int nf = 0; nf < 4; nf++) {
        int col = n0 + wc * 64 + nf * 16 + (lane & 15);
#pragma unroll
        for (int mf = 0; mf < 4; mf++) {
            int rbase = m0 + wr * 64 + mf * 16 + (lane >> 4) * 4;
#pragma unroll
            for (int rr = 0; rr < 4; rr++)
                C[(size_t)(rbase + rr) * 256 + col] = (__bf16)acc[mf][nf][rr];
        }
    }
}

// ---------------------------------------------------------------------------
// Fused GAT layer v6: one graph/block, 4 waves, wave owns 64 cols = 2 heads.
// accE ELIMINATED: es/ed computed in-register from acc (32 FMAs + shfl
// butterfly per sd,head) + ba offset -> total regs ~150 -> 3 waves/SIMD.
// E stored pre-scaled by log2(e); P uses native exp2.
// History: (256,4) spilled (R6); reg double-buffer spilled (R8); accE cost
// 16 AGPR and capped occupancy at 2 waves/SIMD (R9).
// Per-wave LDS (5376 B): V@0 (4K) E@4096 (1K) inv@5120; a_lds 2KB block-wide.
// ONE barrier (WAR: all h A-reads before any epilogue h-write).
// ---------------------------------------------------------------------------
__global__ __launch_bounds__(256, 3)
void fused_gat_layer(const unsigned long long* __restrict__ masks,
                     __bf16* h,
                     const __bf16* __restrict__ Wb,
                     const float* __restrict__ bias,
                     const float* __restrict__ a_vec,   // [8][64] this layer
                     const float* __restrict__ ba)      // [16] this layer
{
    __shared__ __align__(16) char smem[4 * 5376 + 2048];
    float* a_lds = (float*)(smem + 4 * 5376);

    const int tid  = threadIdx.x;
    const int lane = tid & 63;
    const int w    = tid >> 6;
    const int q    = lane >> 4;
    const int d15  = lane & 15;
    const int g    = blockIdx.x;
    const size_t m0 = (size_t)g * 64;

    char*  wbase = smem + w * 5376;
    float* E     = (float*)(wbase + 4096);
    float* invv  = (float*)(wbase + 5120);

    // stage a_vec (visible after the barrier)
    a_lds[tid]       = a_vec[tid];
    a_lds[tid + 256] = a_vec[tid + 256];

    // --- GEMM: acc[mf][nf] = raw hp tile (no bias), wave's 64 cols ---
    f32x4 acc[4][4];
#pragma unroll
    for (int i = 0; i < 4; i++)
#pragma unroll
        for (int j = 0; j < 4; j++) acc[i][j] = (f32x4){0.f, 0.f, 0.f, 0.f};

#pragma unroll 2
    for (int ks = 0; ks < 8; ks++) {
        const int k0 = ks * 32 + q * 8;
        bf16x8 ah[4];
#pragma unroll
        for (int mf = 0; mf < 4; mf++)
            ah[mf] = *(const bf16x8*)(h + (m0 + mf * 16 + d15) * 256 + k0);
#pragma unroll
        for (int nf = 0; nf < 4; nf++) {
            bf16x8 bh = *(const bf16x8*)(Wb + (size_t)(w * 64 + nf * 16 + d15) * 256 + k0);
#pragma unroll
            for (int mf = 0; mf < 4; mf++)
                acc[mf][nf] = MFMA16(ah[mf], bh, acc[mf][nf]);
        }
    }

    // All h A-reads complete before any epilogue h-write (only barrier).
    __syncthreads();

    // adjacency masks
    unsigned long long msk[4];
#pragma unroll
    for (int mf = 0; mf < 4; mf++) msk[mf] = masks[g * 64 + mf * 16 + d15];

    // --- per-head: es/ed derive -> V frags -> P synth -> PV MFMA -> store ---
#pragma unroll
    for (int hl = 0; hl < 2; hl++) {
        const int head = 2 * w + hl;

        // es/ed from acc in-register (pre-bias acc; bias.a folded via ba),
        // stored into E pre-scaled by log2(e).
#pragma unroll
        for (int sd = 0; sd < 2; sd++) {
            float a0 = a_lds[head * 64 + sd * 32 + d15];
            float a1 = a_lds[head * 64 + sd * 32 + 16 + d15];
            float tmp[4][4];
#pragma unroll
            for (int mf = 0; mf < 4; mf++)
#pragma unroll
                for (int rr = 0; rr < 4; rr++)
                    tmp[mf][rr] = acc[mf][2 * hl][rr] * a0 + acc[mf][2 * hl + 1][rr] * a1;
#pragma unroll
            for (int off = 1; off <= 8; off <<= 1)
#pragma unroll
                for (int mf = 0; mf < 4; mf++)
#pragma unroll
                    for (int rr = 0; rr < 4; rr++)
                        tmp[mf][rr] += __shfl_xor(tmp[mf][rr], off);
            float bac = ba[2 * head + sd];
            if (d15 == 0) {
#pragma unroll
                for (int mf = 0; mf < 4; mf++)
#pragma unroll
                    for (int rr = 0; rr < 4; rr++)
                        E[(hl * 2 + sd) * 64 + mf * 16 + q * 4 + rr] =
                            (tmp[mf][rr] + bac) * LOG2E;
            }
        }

        // V fragments for this head (wave-private, swizzled [d][j] bf16)
#pragma unroll
        for (int nfl = 0; nfl < 2; nfl++) {
            const int nf = hl * 2 + nfl;
            const int d  = nfl * 16 + d15;
            const float bv = bias[w * 64 + nf * 16 + d15];
            char* vb = wbase + d * 128;
#pragma unroll
            for (int mf = 0; mf < 4; mf++) {
                int s   = mf * 2 + (q >> 1);
                int off = ((s ^ (d & 7)) << 4) + (q & 1) * 8;
                bf16x4 h4;
#pragma unroll
                for (int rr = 0; rr < 4; rr++)
                    h4[rr] = (__bf16)(acc[mf][nf][rr] + bv);
                *(bf16x4*)(vb + off) = h4;
            }
        }

        float ev = E[(hl * 2 + 1) * 64 + lane];
#pragma unroll
        for (int off = 32; off; off >>= 1) ev = fmaxf(ev, __shfl_xor(ev, off));

        float esi[4], mh[4];
#pragma unroll
        for (int mf = 0; mf < 4; mf++) {
            esi[mf] = E[(hl * 2) * 64 + mf * 16 + d15];
            mh[mf]  = leaky(esi[mf] + ev);
        }

        f32x4 pv[4][2];
#pragma unroll
        for (int mf = 0; mf < 4; mf++) {
            pv[mf][0] = (f32x4){0.f, 0.f, 0.f, 0.f};
            pv[mf][1] = (f32x4){0.f, 0.f, 0.f, 0.f};
        }
        float rs[4] = {0.f, 0.f, 0.f, 0.f};

#pragma unroll
        for (int ksj = 0; ksj < 2; ksj++) {
            const int j8 = ksj * 32 + q * 8;
            const int s  = ksj * 4 + q;
            bf16x8 vh[2];
#pragma unroll
            for (int nf2 = 0; nf2 < 2; nf2++) {
                int d = nf2 * 16 + d15;
                vh[nf2] = *(const bf16x8*)(wbase + d * 128 + ((s ^ (d & 7)) << 4));
            }
            float edv[8];
#pragma unroll
            for (int e = 0; e < 8; e++) edv[e] = E[(hl * 2 + 1) * 64 + j8 + e];

#pragma unroll
            for (int mf = 0; mf < 4; mf++) {
                unsigned int mb = (unsigned int)(msk[mf] >> j8) & 0xffu;
                bf16x8 ph;
                float rsum = 0.f;
#pragma unroll
                for (int e = 0; e < 8; e++) {
                    float t = leaky(esi[mf] + edv[e]);   // log2-scaled
                    float p = ((mb >> e) & 1u)
                                ? __builtin_amdgcn_exp2f(t - mh[mf]) : 0.f;
                    rsum += p;
                    ph[e] = (__bf16)p;
                }
                rs[mf] += rsum;
#pragma unroll
                for (int nf2 = 0; nf2 < 2; nf2++)
                    pv[mf][nf2] = MFMA16(ph, vh[nf2], pv[mf][nf2]);
            }
        }

        // row sums -> 1/s
#pragma unroll
        for (int mf = 0; mf < 4; mf++) {
            float r = rs[mf];
            r += __shfl_xor(r, 16);
            r += __shfl_xor(r, 32);
            if (q == 0) invv[mf * 16 + d15] = (r > 0.f) ? 1.f / r : 0.f;
        }

        // epilogue: scale, residual, ELU, bf16 store (wave-own cols only)
#pragma unroll
        for (int mf = 0; mf < 4; mf++) {
#pragma unroll
            for (int nf2 = 0; nf2 < 2; nf2++) {
                int d = head * 32 + nf2 * 16 + d15;
#pragma unroll
                for (int rr = 0; rr < 4; rr++) {
                    int i = mf * 16 + q * 4 + rr;
                    float inv = invv[i];
                    size_t idx = (m0 + i) * 256 + d;
                    float o = pv[mf][nf2][rr] * inv + (float)h[idx];
                    o = o > 0.f ? o : __expf(o) - 1.f;
                    h[idx] = (__bf16)o;
                }
            }
        }
    }
}

// ---------------------------------------------------------------------------
// Masked mean-pool + 3-layer MLP + elu + 1.5. One block per graph.
// ---------------------------------------------------------------------------
__global__ __launch_bounds__(256)
void pool_mlp(const unsigned long long* __restrict__ masks,
              const __bf16* __restrict__ h,
              const float* __restrict__ W1, const float* __restrict__ b1,
              const float* __restrict__ W2, const float* __restrict__ b2,
              const float* __restrict__ W3, const float* __restrict__ b3,
              float* __restrict__ out)
{
    __shared__ float lds_g[256];
    __shared__ float lds_z1[128];
    __shared__ float lds_z2[128];
    __shared__ unsigned long long lds_m;
    __shared__ float lds_invcnt;

    const int tid = threadIdx.x;
    const int b   = blockIdx.x;
    const __bf16* hb = h + (size_t)b * 16384;

    if (tid < 64) {
        unsigned long long rowm = masks[b * 64 + tid];
        unsigned long long m = __ballot((rowm >> tid) & 1ULL);
        if (tid == 0) { lds_m = m; lds_invcnt = 1.f / (float)__popcll(m); }
    }
    __syncthreads();

    unsigned long long msk = lds_m;
    float invc = lds_invcnt;
    float gsum = 0.f;
    for (int n = 0; n < 64; n++)
        if ((msk >> n) & 1ULL) gsum += (float)hb[n * 256 + tid];
    lds_g[tid] = gsum * invc;
    __syncthreads();

    if (tid < 128) {
        const float* wr = W1 + tid * 256;
        float z = 0.f;
#pragma unroll 8
        for (int k = 0; k < 256; k += 4) {
            float4 wv = *(const float4*)&wr[k];
            z += wv.x * lds_g[k] + wv.y * lds_g[k + 1] + wv.z * lds_g[k + 2] + wv.w * lds_g[k + 3];
        }
        z += b1[tid];
        lds_z1[tid] = z > 0.f ? z : 0.f;
    }
    __syncthreads();

    if (tid < 128) {
        const float* wr = W2 + tid * 128;
        float z = 0.f;
#pragma unroll 8
        for (int k = 0; k < 128; k += 4) {
            float4 wv = *(const float4*)&wr[k];
            z += wv.x * lds_z1[k] + wv.y * lds_z1[k + 1] + wv.z * lds_z1[k + 2] + wv.w * lds_z1[k + 3];
        }
        z += b2[tid];
        lds_z2[tid] = z > 0.f ? z : 0.f;
    }
    __syncthreads();

    if (tid < 64) {
        float p = W3[tid] * lds_z2[tid] + W3[tid + 64] * lds_z2[tid + 64];
        for (int off = 32; off; off >>= 1) p += __shfl_down(p, off);
        if (tid == 0) {
            float z = p + b3[0];
            out[b] = (z > 0.f ? z : __expf(z) - 1.f) + 1.5f;
        }
    }
}

// ---------------------------------------------------------------------------
extern "C" void kernel_launch(void* const* d_in, const int* in_sizes, int n_in,
                              void* d_out, int out_size, void* d_ws, size_t ws_size,
                              hipStream_t stream)
{
    const float* x      = (const float*)d_in[0];
    const float* A      = (const float*)d_in[1];
    const float* W_emb  = (const float*)d_in[2];
    const float* gat_W  = (const float*)d_in[3];
    const float* gat_b  = (const float*)d_in[4];
    const float* gat_a  = (const float*)d_in[5];
    const float* fc_W1  = (const float*)d_in[6];
    const float* fc_b1  = (const float*)d_in[7];
    const float* fc_W2  = (const float*)d_in[8];
    const float* fc_b2  = (const float*)d_in[9];
    const float* fc_W3  = (const float*)d_in[10];
    const float* fc_b3  = (const float*)d_in[11];
    float* out = (float*)d_out;

    // workspace (~86 MB):
    //   h  bf16 [131072][256]   @ 0          67108864
    //   xb bf16 [131072][64]    @ 67108864   16777216
    //   Wemb_b [256][64]        @ 83886080   32768
    //   Wb [6][256][256] bf16   @ 83918848   786432
    //   ba [6][16] f32          @ 84705280   384
    //   masks u64 [2048][64]    @ 84705664   1048576
    char* ws = (char*)d_ws;
    __bf16* h      = (__bf16*)ws;
    __bf16* xb     = (__bf16*)(ws + 67108864);
    __bf16* Wemb_b = (__bf16*)(ws + 83886080);
    __bf16* Wb     = (__bf16*)(ws + 83918848);
    float*  ba     = (float*)(ws + 84705280);
    unsigned long long* masks = (unsigned long long*)(ws + 84705664);

    int conv_total = L_LAYERS * 65536 + L_LAYERS * 16;
    convert_weights<<<(conv_total + 255) / 256, 256, 0, stream>>>(
        W_emb, gat_W, gat_a, gat_b, Wemb_b, Wb, ba);
    convert_x<<<M_FULL * 64 / 256, 256, 0, stream>>>(x, xb);
    build_masks<<<B_GRAPHS, 256, 0, stream>>>(A, masks);

    gemm_embed<<<dim3(M_FULL / 128, 2), 256, 0, stream>>>(xb, Wemb_b, h);

    for (int l = 0; l < L_LAYERS; l++) {
        fused_gat_layer<<<B_GRAPHS, 256, 0, stream>>>(
            masks, h,
            Wb + (size_t)l * WSLAB,
            gat_b + l * D_DIM,
            gat_a + (size_t)l * 512,
            ba + l * 16);
    }

    pool_mlp<<<B_GRAPHS, 256, 0, stream>>>(masks, h, fc_W1, fc_b1,
                                           fc_W2, fc_b2, fc_W3, fc_b3, out);
}

// Round 11
// 646.488 us; speedup vs baseline: 4.8064x; 1.2666x over previous
//
#include <hip/hip_runtime.h>
#include <cstdint>
#include <cstddef>

#define B_GRAPHS 2048
#define N_NODES  64
#define FIN      49
#define D_DIM    256
#define H_HEADS  8
#define DK_DIM   32
#define L_LAYERS 6
#define ALPHA    0.2f
#define LOG2E    1.4426950408889634f

#define M_FULL     (B_GRAPHS * N_NODES)           // 131072 rows
#define WSLAB      (256 * 256)                     // per-layer weight slab elems

typedef __bf16 bf16x8 __attribute__((ext_vector_type(8)));
typedef __bf16 bf16x4 __attribute__((ext_vector_type(4)));
typedef float  f32x4  __attribute__((ext_vector_type(4)));

#define MFMA16(a, b, c) __builtin_amdgcn_mfma_f32_16x16x32_bf16(a, b, c, 0, 0, 0)

__device__ __forceinline__ float leaky(float t) { return t > 0.f ? t : ALPHA * t; }

// ---------------------------------------------------------------------------
// Weight prep: W -> single bf16; ba[l][c] = a[l,h,sd*32:] . b[l,h*32:] (f32).
// ---------------------------------------------------------------------------
__global__ void convert_weights(const float* __restrict__ W_emb,
                                const float* __restrict__ gat_W,
                                const float* __restrict__ gat_a,
                                const float* __restrict__ gat_b,
                                __bf16* __restrict__ Wemb_b,   // [256][64]
                                __bf16* __restrict__ Wb,       // [6][256][256]
                                float* __restrict__ ba)        // [6][16]
{
    int idx = blockIdx.x * 256 + threadIdx.x;
    if (idx < 256 * 64) {
        int n = idx >> 6, k = idx & 63;
        float f = (k < FIN) ? W_emb[n * FIN + k] : 0.f;
        Wemb_b[idx] = (__bf16)f;
    }
    if (idx < L_LAYERS * 65536) {
        Wb[idx] = (__bf16)gat_W[idx];
    }
    int o2 = idx - L_LAYERS * 65536;
    if (o2 >= 0 && o2 < L_LAYERS * 16) {
        int l = o2 >> 4, c = o2 & 15;
        int hh = c >> 1, sd = c & 1;
        const float* av = gat_a + l * 512 + hh * 64 + sd * 32;
        const float* bp = gat_b + l * 256 + hh * 32;
        float s = 0.f;
        for (int d = 0; d < 32; d++) s += av[d] * bp[d];
        ba[o2] = s;
    }
}

// x [M][49] fp32 -> xb [M][64] bf16 (zero-padded)
__global__ void convert_x(const float* __restrict__ x, __bf16* __restrict__ xb)
{
    int idx = blockIdx.x * 256 + threadIdx.x;
    int m = idx >> 6, k = idx & 63;
    xb[idx] = (__bf16)((k < FIN) ? x[m * FIN + k] : 0.f);
}

// ---------------------------------------------------------------------------
// Adjacency bitmasks, once: masks[g][r] bit j = A[g][r][j] > 0.
// ---------------------------------------------------------------------------
__global__ void build_masks(const float* __restrict__ A,
                            unsigned long long* __restrict__ masks)
{
    int g = blockIdx.x;
    int lane = threadIdx.x & 63;
    int w = threadIdx.x >> 6;
    const float* Ab = A + (size_t)g * 4096;
    for (int rr = 0; rr < 16; rr++) {
        int r = w * 16 + rr;
        unsigned long long m = __ballot(Ab[r * 64 + lane] > 0.f);
        if (lane == 0) masks[g * 64 + r] = m;
    }
}

// ---------------------------------------------------------------------------
// Embed GEMM: h[M,256] = bf16(x @ W_emb^T).  bf16 MFMA, fp32 acc.
// ---------------------------------------------------------------------------
__device__ __forceinline__ int swz(int r, int s) {
    return r * 64 + (((s ^ (r & 3)) << 4));
}

__global__ __launch_bounds__(256, 2)
void gemm_embed(const __bf16* __restrict__ Ab, const __bf16* __restrict__ Bb,
                __bf16* __restrict__ C)
{
    const int K = 64;
    __shared__ __align__(16) char lds[2][16384];   // A@0 (8K), B@8192 (8K)

    const int tid  = threadIdx.x;
    const int m0   = blockIdx.x * 128;
    const int n0   = blockIdx.y * 128;
    const int lane = tid & 63;
    const int wid  = tid >> 6;
    const int wr   = wid >> 1, wc = wid & 1;

    bf16x8 regA[2], regB[2];
    f32x4 acc[4][4];
#pragma unroll
    for (int i = 0; i < 4; i++)
#pragma unroll
        for (int j = 0; j < 4; j++) acc[i][j] = (f32x4){0.f, 0.f, 0.f, 0.f};

    auto load_stage = [&](int k0) {
#pragma unroll
        for (int g = 0; g < 2; g++) {
            int u = g * 256 + tid, r = u >> 2, s = u & 3;
            regA[g] = *(const bf16x8*)(Ab + (size_t)(m0 + r) * K + k0 + s * 8);
            regB[g] = *(const bf16x8*)(Bb + (size_t)(n0 + r) * K + k0 + s * 8);
        }
    };
    auto write_stage = [&](int buf) {
        char* base = lds[buf];
#pragma unroll
        for (int g = 0; g < 2; g++) {
            int u = g * 256 + tid, r = u >> 2, s = u & 3;
            int off = swz(r, s);
            *(bf16x8*)(base + off)        = regA[g];
            *(bf16x8*)(base + 8192 + off) = regB[g];
        }
    };
    auto compute = [&](int buf) {
        const char* base = lds[buf];
        const int s = lane >> 4;
        bf16x8 ah[4];
#pragma unroll
        for (int mf = 0; mf < 4; mf++)
            ah[mf] = *(const bf16x8*)(base + swz(wr * 64 + mf * 16 + (lane & 15), s));
#pragma unroll
        for (int nf = 0; nf < 4; nf++) {
            bf16x8 bh = *(const bf16x8*)(base + 8192 +
                            swz(wc * 64 + nf * 16 + (lane & 15), s));
#pragma unroll
            for (int mf = 0; mf < 4; mf++)
                acc[mf][nf] = MFMA16(ah[mf], bh, acc[mf][nf]);
        }
    };

    load_stage(0);
    write_stage(0);
    load_stage(32);
    __syncthreads();
    compute(0);
    write_stage(1);
    __syncthreads();
    compute(1);

#pragma unroll
    for (int nf = 0; nf < 4; nf++) {
        int col = n0 + wc * 64 + nf * 16 + (lane & 15);
#pragma unroll
        for (int mf = 0; mf < 4; mf++) {
            int rbase = m0 + wr * 64 + mf * 16 + (lane >> 4) * 4;
#pragma unroll
            for (int rr = 0; rr < 4; rr++)
                C[(size_t)(rbase + rr) * 256 + col] = (__bf16)acc[mf][nf][rr];
        }
    }
}

// ---------------------------------------------------------------------------
// Fused GAT layer v7: one graph/block, 4 waves, wave owns 64 cols = 2 heads.
// KEY CHANGE vs v6: the graph's h-tile (32 KB) is staged into LDS ONCE
// (8 coalesced independent loads/thread = ONE latency window instead of 8
// serialized k-step rounds), XOR-swizzled for conflict-free ds_read_b128.
// GEMM A-frags come from LDS; B weights get 1-step register prefetch
// (affordable: LDS caps at 2 blocks/CU so VGPR budget is free).
// Epilogue residual reads the LDS copy -> global h re-read eliminated AND
// the cross-wave WAR hazard is gone (nobody reads global h after staging).
// History: (256,4) spilled (R6); 3-term reg-dbuf spilled (R8); accE cost 16
// AGPR (R9); occupancy 22->31% bought nothing (R10: latency-, not TLP-bound).
// LDS map: A-tile 32KB @0 | V[w] 4KB @32768+4096w | E/inv @49152+1280w |
//          a_lds 2KB @54272  (total 56320, 2 blocks/CU)
// ONE barrier (staging visibility only).
// ---------------------------------------------------------------------------
__global__ __launch_bounds__(256, 2)
void fused_gat_layer(const unsigned long long* __restrict__ masks,
                     __bf16* h,
                     const __bf16* __restrict__ Wb,
                     const float* __restrict__ bias,
                     const float* __restrict__ a_vec,   // [8][64] this layer
                     const float* __restrict__ ba)      // [16] this layer
{
    __shared__ __align__(16) char smem[56320];
    float* a_lds = (float*)(smem + 54272);

    const int tid  = threadIdx.x;
    const int lane = tid & 63;
    const int w    = tid >> 6;
    const int q    = lane >> 4;
    const int d15  = lane & 15;
    const int g    = blockIdx.x;
    const size_t m0 = (size_t)g * 64;

    char*  vwbase = smem + 32768 + w * 4096;
    float* E      = (float*)(smem + 49152 + w * 1280);
    float* invv   = (float*)(smem + 49152 + w * 1280 + 1024);

    // --- stage h-tile: coalesced global read, swizzled LDS write ---
    const char* hbase = (const char*)(h + m0 * 256);
    {
        bf16x8 st[8];
#pragma unroll
        for (int it = 0; it < 8; it++)
            st[it] = *(const bf16x8*)(hbase + it * 4096 + tid * 16);
#pragma unroll
        for (int it = 0; it < 8; it++) {
            int off  = it * 4096 + tid * 16;
            int row  = off >> 9;
            int slot = (off >> 4) & 31;
            *(bf16x8*)(smem + row * 512 + (((slot ^ (row & 7)) << 4))) = st[it];
        }
    }
    // stage a_vec
    a_lds[tid]       = a_vec[tid];
    a_lds[tid + 256] = a_vec[tid + 256];

    // --- GEMM accumulators + B prefetch (k-step 0) ---
    f32x4 acc[4][4];
#pragma unroll
    for (int i = 0; i < 4; i++)
#pragma unroll
        for (int j = 0; j < 4; j++) acc[i][j] = (f32x4){0.f, 0.f, 0.f, 0.f};

    bf16x8 bhc[4], bhn[4];
#pragma unroll
    for (int nf = 0; nf < 4; nf++)
        bhc[nf] = *(const bf16x8*)(Wb + (size_t)(w * 64 + nf * 16 + d15) * 256 + q * 8);

    __syncthreads();   // staging visible; the ONLY barrier

    // --- GEMM from LDS, B prefetched one step ahead ---
#pragma unroll
    for (int ks = 0; ks < 8; ks++) {
        if (ks < 7) {
            const int k0n = (ks + 1) * 32 + q * 8;
#pragma unroll
            for (int nf = 0; nf < 4; nf++)
                bhn[nf] = *(const bf16x8*)(Wb + (size_t)(w * 64 + nf * 16 + d15) * 256 + k0n);
        }
        bf16x8 ah[4];
        const int slotb = ks * 4 + q;
#pragma unroll
        for (int mf = 0; mf < 4; mf++) {
            int r = mf * 16 + d15;
            ah[mf] = *(const bf16x8*)(smem + r * 512 + (((slotb ^ (r & 7)) << 4)));
        }
#pragma unroll
        for (int nf = 0; nf < 4; nf++)
#pragma unroll
            for (int mf = 0; mf < 4; mf++)
                acc[mf][nf] = MFMA16(ah[mf], bhc[nf], acc[mf][nf]);
#pragma unroll
        for (int nf = 0; nf < 4; nf++) bhc[nf] = bhn[nf];
    }

    // adjacency masks
    unsigned long long msk[4];
#pragma unroll
    for (int mf = 0; mf < 4; mf++) msk[mf] = masks[g * 64 + mf * 16 + d15];

    // --- per-head: es/ed derive -> V frags -> P synth -> PV MFMA -> store ---
#pragma unroll
    for (int hl = 0; hl < 2; hl++) {
        const int head = 2 * w + hl;

        // es/ed from acc in-register; E pre-scaled by log2(e)
#pragma unroll
        for (int sd = 0; sd < 2; sd++) {
            float a0 = a_lds[head * 64 + sd * 32 + d15];
            float a1 = a_lds[head * 64 + sd * 32 + 16 + d15];
            float tmp[4][4];
#pragma unroll
            for (int mf = 0; mf < 4; mf++)
#pragma unroll
                for (int rr = 0; rr < 4; rr++)
                    tmp[mf][rr] = acc[mf][2 * hl][rr] * a0 + acc[mf][2 * hl + 1][rr] * a1;
#pragma unroll
            for (int off = 1; off <= 8; off <<= 1)
#pragma unroll
                for (int mf = 0; mf < 4; mf++)
#pragma unroll
                    for (int rr = 0; rr < 4; rr++)
                        tmp[mf][rr] += __shfl_xor(tmp[mf][rr], off);
            float bac = ba[2 * head + sd];
            if (d15 == 0) {
#pragma unroll
                for (int mf = 0; mf < 4; mf++)
#pragma unroll
                    for (int rr = 0; rr < 4; rr++)
                        E[(hl * 2 + sd) * 64 + mf * 16 + q * 4 + rr] =
                            (tmp[mf][rr] + bac) * LOG2E;
            }
        }

        // V fragments for this head (wave-private, swizzled [d][j] bf16)
#pragma unroll
        for (int nfl = 0; nfl < 2; nfl++) {
            const int nf = hl * 2 + nfl;
            const int d  = nfl * 16 + d15;
            const float bv = bias[w * 64 + nf * 16 + d15];
            char* vb = vwbase + d * 128;
#pragma unroll
            for (int mf = 0; mf < 4; mf++) {
                int s   = mf * 2 + (q >> 1);
                int off = ((s ^ (d & 7)) << 4) + (q & 1) * 8;
                bf16x4 h4;
#pragma unroll
                for (int rr = 0; rr < 4; rr++)
                    h4[rr] = (__bf16)(acc[mf][nf][rr] + bv);
                *(bf16x4*)(vb + off) = h4;
            }
        }

        float ev = E[(hl * 2 + 1) * 64 + lane];
#pragma unroll
        for (int off = 32; off; off >>= 1) ev = fmaxf(ev, __shfl_xor(ev, off));

        float esi[4], mh[4];
#pragma unroll
        for (int mf = 0; mf < 4; mf++) {
            esi[mf] = E[(hl * 2) * 64 + mf * 16 + d15];
            mh[mf]  = leaky(esi[mf] + ev);
        }

        f32x4 pv[4][2];
#pragma unroll
        for (int mf = 0; mf < 4; mf++) {
            pv[mf][0] = (f32x4){0.f, 0.f, 0.f, 0.f};
            pv[mf][1] = (f32x4){0.f, 0.f, 0.f, 0.f};
        }
        float rs[4] = {0.f, 0.f, 0.f, 0.f};

#pragma unroll
        for (int ksj = 0; ksj < 2; ksj++) {
            const int j8 = ksj * 32 + q * 8;
            const int s  = ksj * 4 + q;
            bf16x8 vh[2];
#pragma unroll
            for (int nf2 = 0; nf2 < 2; nf2++) {
                int d = nf2 * 16 + d15;
                vh[nf2] = *(const bf16x8*)(vwbase + d * 128 + ((s ^ (d & 7)) << 4));
            }
            float edv[8];
#pragma unroll
            for (int e = 0; e < 8; e++) edv[e] = E[(hl * 2 + 1) * 64 + j8 + e];

#pragma unroll
            for (int mf = 0; mf < 4; mf++) {
                unsigned int mb = (unsigned int)(msk[mf] >> j8) & 0xffu;
                bf16x8 ph;
                float rsum = 0.f;
#pragma unroll
                for (int e = 0; e < 8; e++) {
                    float t = leaky(esi[mf] + edv[e]);   // log2-scaled
                    float p = ((mb >> e) & 1u)
                                ? __builtin_amdgcn_exp2f(t - mh[mf]) : 0.f;
                    rsum += p;
                    ph[e] = (__bf16)p;
                }
                rs[mf] += rsum;
#pragma unroll
                for (int nf2 = 0; nf2 < 2; nf2++)
                    pv[mf][nf2] = MFMA16(ph, vh[nf2], pv[mf][nf2]);
            }
        }

        // row sums -> 1/s
#pragma unroll
        for (int mf = 0; mf < 4; mf++) {
            float r = rs[mf];
            r += __shfl_xor(r, 16);
            r += __shfl_xor(r, 32);
            if (q == 0) invv[mf * 16 + d15] = (r > 0.f) ? 1.f / r : 0.f;
        }

        // epilogue: scale, residual (from LDS stage), ELU, bf16 store
#pragma unroll
        for (int mf = 0; mf < 4; mf++) {
#pragma unroll
            for (int nf2 = 0; nf2 < 2; nf2++) {
                int d = head * 32 + nf2 * 16 + d15;
                int dslot = d >> 3, dby = (d & 7) << 1;
#pragma unroll
                for (int rr = 0; rr < 4; rr++) {
                    int i = mf * 16 + q * 4 + rr;
                    float inv = invv[i];
                    float old = (float)*(const __bf16*)(
                        smem + i * 512 + (((dslot ^ (i & 7)) << 4)) + dby);
                    float o = pv[mf][nf2][rr] * inv + old;
                    o = o > 0.f ? o : __expf(o) - 1.f;
                    h[(m0 + i) * 256 + d] = (__bf16)o;
                }
            }
        }
    }
}

// ---------------------------------------------------------------------------
// Masked mean-pool + 3-layer MLP + elu + 1.5. One block per graph.
// ---------------------------------------------------------------------------
__global__ __launch_bounds__(256)
void pool_mlp(const unsigned long long* __restrict__ masks,
              const __bf16* __restrict__ h,
              const float* __restrict__ W1, const float* __restrict__ b1,
              const float* __restrict__ W2, const float* __restrict__ b2,
              const float* __restrict__ W3, const float* __restrict__ b3,
              float* __restrict__ out)
{
    __shared__ float lds_g[256];
    __shared__ float lds_z1[128];
    __shared__ float lds_z2[128];
    __shared__ unsigned long long lds_m;
    __shared__ float lds_invcnt;

    const int tid = threadIdx.x;
    const int b   = blockIdx.x;
    const __bf16* hb = h + (size_t)b * 16384;

    if (tid < 64) {
        unsigned long long rowm = masks[b * 64 + tid];
        unsigned long long m = __ballot((rowm >> tid) & 1ULL);
        if (tid == 0) { lds_m = m; lds_invcnt = 1.f / (float)__popcll(m); }
    }
    __syncthreads();

    unsigned long long msk = lds_m;
    float invc = lds_invcnt;
    float gsum = 0.f;
    for (int n = 0; n < 64; n++)
        if ((msk >> n) & 1ULL) gsum += (float)hb[n * 256 + tid];
    lds_g[tid] = gsum * invc;
    __syncthreads();

    if (tid < 128) {
        const float* wr = W1 + tid * 256;
        float z = 0.f;
#pragma unroll 8
        for (int k = 0; k < 256; k += 4) {
            float4 wv = *(const float4*)&wr[k];
            z += wv.x * lds_g[k] + wv.y * lds_g[k + 1] + wv.z * lds_g[k + 2] + wv.w * lds_g[k + 3];
        }
        z += b1[tid];
        lds_z1[tid] = z > 0.f ? z : 0.f;
    }
    __syncthreads();

    if (tid < 128) {
        const float* wr = W2 + tid * 128;
        float z = 0.f;
#pragma unroll 8
        for (int k = 0; k < 128; k += 4) {
            float4 wv = *(const float4*)&wr[k];
            z += wv.x * lds_z1[k] + wv.y * lds_z1[k + 1] + wv.z * lds_z1[k + 2] + wv.w * lds_z1[k + 3];
        }
        z += b2[tid];
        lds_z2[tid] = z > 0.f ? z : 0.f;
    }
    __syncthreads();

    if (tid < 64) {
        float p = W3[tid] * lds_z2[tid] + W3[tid + 64] * lds_z2[tid + 64];
        for (int off = 32; off; off >>= 1) p += __shfl_down(p, off);
        if (tid == 0) {
            float z = p + b3[0];
            out[b] = (z > 0.f ? z : __expf(z) - 1.f) + 1.5f;
        }
    }
}

// ---------------------------------------------------------------------------
extern "C" void kernel_launch(void* const* d_in, const int* in_sizes, int n_in,
                              void* d_out, int out_size, void* d_ws, size_t ws_size,
                              hipStream_t stream)
{
    const float* x      = (const float*)d_in[0];
    const float* A      = (const float*)d_in[1];
    const float* W_emb  = (const float*)d_in[2];
    const float* gat_W  = (const float*)d_in[3];
    const float* gat_b  = (const float*)d_in[4];
    const float* gat_a  = (const float*)d_in[5];
    const float* fc_W1  = (const float*)d_in[6];
    const float* fc_b1  = (const float*)d_in[7];
    const float* fc_W2  = (const float*)d_in[8];
    const float* fc_b2  = (const float*)d_in[9];
    const float* fc_W3  = (const float*)d_in[10];
    const float* fc_b3  = (const float*)d_in[11];
    float* out = (float*)d_out;

    // workspace (~86 MB):
    //   h  bf16 [131072][256]   @ 0          67108864
    //   xb bf16 [131072][64]    @ 67108864   16777216
    //   Wemb_b [256][64]        @ 83886080   32768
    //   Wb [6][256][256] bf16   @ 83918848   786432
    //   ba [6][16] f32          @ 84705280   384
    //   masks u64 [2048][64]    @ 84705664   1048576
    char* ws = (char*)d_ws;
    __bf16* h      = (__bf16*)ws;
    __bf16* xb     = (__bf16*)(ws + 67108864);
    __bf16* Wemb_b = (__bf16*)(ws + 83886080);
    __bf16* Wb     = (__bf16*)(ws + 83918848);
    float*  ba     = (float*)(ws + 84705280);
    unsigned long long* masks = (unsigned long long*)(ws + 84705664);

    int conv_total = L_LAYERS * 65536 + L_LAYERS * 16;
    convert_weights<<<(conv_total + 255) / 256, 256, 0, stream>>>(
        W_emb, gat_W, gat_a, gat_b, Wemb_b, Wb, ba);
    convert_x<<<M_FULL * 64 / 256, 256, 0, stream>>>(x, xb);
    build_masks<<<B_GRAPHS, 256, 0, stream>>>(A, masks);

    gemm_embed<<<dim3(M_FULL / 128, 2), 256, 0, stream>>>(xb, Wemb_b, h);

    for (int l = 0; l < L_LAYERS; l++) {
        fused_gat_layer<<<B_GRAPHS, 256, 0, stream>>>(
            masks, h,
            Wb + (size_t)l * WSLAB,
            gat_b + l * D_DIM,
            gat_a + (size_t)l * 512,
            ba + l * 16);
    }

    pool_mlp<<<B_GRAPHS, 256, 0, stream>>>(masks, h, fc_W1, fc_b1,
                                           fc_W2, fc_b2, fc_W3, fc_b3, out);
}

// Round 12
// 569.617 us; speedup vs baseline: 5.4550x; 1.1350x over previous
//
#include <hip/hip_runtime.h>
#include <cstdint>
#include <cstddef>

#define B_GRAPHS 2048
#define N_NODES  64
#define FIN      49
#define D_DIM    256
#define H_HEADS  8
#define DK_DIM   32
#define L_LAYERS 6
#define ALPHA    0.2f
#define LOG2E    1.4426950408889634f

#define M_FULL     (B_GRAPHS * N_NODES)           // 131072 rows
#define WSLAB      (256 * 256)                     // per-layer weight slab elems

typedef __bf16 bf16x8 __attribute__((ext_vector_type(8)));
typedef __bf16 bf16x4 __attribute__((ext_vector_type(4)));
typedef float  f32x4  __attribute__((ext_vector_type(4)));

#define MFMA16(a, b, c) __builtin_amdgcn_mfma_f32_16x16x32_bf16(a, b, c, 0, 0, 0)

__device__ __forceinline__ float leaky(float t) { return t > 0.f ? t : ALPHA * t; }

// LDS map (73632 B total, 2 blocks/CU):
#define LDS_H     0        // h tile [64 rows][256 cols] bf16 swizzled, 32768 B
#define LDS_V     32768    // V per wave 4096 B (x4); aliased by xb stage + pool g/z1/z2
#define LDS_EI    49152    // E(1024)+inv(256) per wave (x4) = 5120
#define LDS_A     54272    // a_vec all layers f32[6][512] = 12288
#define LDS_BIAS  66560    // gat_b all layers f32[6][256] = 6144
#define LDS_BA    72704    // ba f32[6][16] = 384
#define LDS_AM    73088    // adjacency masks u64[64] = 512
#define LDS_VALID 73600    // valid bitmask u64 + invcnt f32
#define LDS_TOTAL 73632

// ---------------------------------------------------------------------------
// Weight prep: W -> single bf16; ba[l][c] = a[l,h,sd*32:] . b[l,h*32:] (f32).
// ---------------------------------------------------------------------------
__global__ void convert_weights(const float* __restrict__ W_emb,
                                const float* __restrict__ gat_W,
                                const float* __restrict__ gat_a,
                                const float* __restrict__ gat_b,
                                __bf16* __restrict__ Wemb_b,   // [256][64]
                                __bf16* __restrict__ Wb,       // [6][256][256]
                                float* __restrict__ ba)        // [6][16]
{
    int idx = blockIdx.x * 256 + threadIdx.x;
    if (idx < 256 * 64) {
        int n = idx >> 6, k = idx & 63;
        float f = (k < FIN) ? W_emb[n * FIN + k] : 0.f;
        Wemb_b[idx] = (__bf16)f;
    }
    if (idx < L_LAYERS * 65536) {
        Wb[idx] = (__bf16)gat_W[idx];
    }
    int o2 = idx - L_LAYERS * 65536;
    if (o2 >= 0 && o2 < L_LAYERS * 16) {
        int l = o2 >> 4, c = o2 & 15;
        int hh = c >> 1, sd = c & 1;
        const float* av = gat_a + l * 512 + hh * 64 + sd * 32;
        const float* bp = gat_b + l * 256 + hh * 32;
        float s = 0.f;
        for (int d = 0; d < 32; d++) s += av[d] * bp[d];
        ba[o2] = s;
    }
}

// x [M][49] fp32 -> xb [M][64] bf16 (zero-padded)
__global__ void convert_x(const float* __restrict__ x, __bf16* __restrict__ xb)
{
    int idx = blockIdx.x * 256 + threadIdx.x;
    int m = idx >> 6, k = idx & 63;
    xb[idx] = (__bf16)((k < FIN) ? x[m * FIN + k] : 0.f);
}

// ---------------------------------------------------------------------------
// MEGA kernel: one block per graph runs the ENTIRE network.
//   stage xb/a/bias/ba + adjacency ballots -> embed GEMM -> 6x (proj GEMM +
//   GAT attention) -> masked mean pool -> 3-layer MLP -> out[g].
// h lives in the swizzled LDS tile for all 6 layers (never touches HBM).
// Per layer: 2 barriers (WAR on shared h-tile). B-weights: 2-deep register
// prefetch from L2. Attention math identical to verified R11 kernel.
// History: (256,4) spilled (R6); 3-term reg-dbuf spilled (R8); accE cost 16
// AGPR (R9); TLP doesn't fix per-wave latency (R10); staging h once = -16% (R11).
// ---------------------------------------------------------------------------
__global__ __launch_bounds__(256, 2)
void mega_gat(const float* __restrict__ A,
              const __bf16* __restrict__ xb,
              const __bf16* __restrict__ Wemb,
              const __bf16* __restrict__ Wb_all,
              const float* __restrict__ gat_b_all,
              const float* __restrict__ a_all,
              const float* __restrict__ ba_all,
              const float* __restrict__ W1, const float* __restrict__ b1,
              const float* __restrict__ W2, const float* __restrict__ b2,
              const float* __restrict__ W3, const float* __restrict__ b3,
              float* __restrict__ out)
{
    __shared__ __align__(16) char smem[LDS_TOTAL];

    const int tid  = threadIdx.x;
    const int lane = tid & 63;
    const int w    = tid >> 6;
    const int q    = lane >> 4;
    const int d15  = lane & 15;
    const int g    = blockIdx.x;

    char*  vwbase   = smem + LDS_V + w * 4096;
    float* E        = (float*)(smem + LDS_EI + w * 1280);
    float* invv     = (float*)(smem + LDS_EI + w * 1280 + 1024);
    float* a_lds    = (float*)(smem + LDS_A);
    float* bias_lds = (float*)(smem + LDS_BIAS);
    float* ba_lds   = (float*)(smem + LDS_BA);
    unsigned long long* Am = (unsigned long long*)(smem + LDS_AM);

    auto h_off = [&](int i, int d) -> int {
        return i * 512 + ((((d >> 3) ^ (i & 7)) << 4)) + ((d & 7) << 1);
    };

    // ---------------- staging (one latency window) ----------------
    {   // xb tile [64][64] bf16 -> V area, swizzled
        const char* src = (const char*)(xb + (size_t)g * 4096);
        bf16x8 t0 = *(const bf16x8*)(src + tid * 16);
        bf16x8 t1 = *(const bf16x8*)(src + 4096 + tid * 16);
        int u0 = tid, u1 = 256 + tid;
        int r0 = u0 >> 3, s0 = u0 & 7;
        int r1 = u1 >> 3, s1 = u1 & 7;
        *(bf16x8*)(smem + LDS_V + r0 * 128 + ((s0 ^ (r0 & 7)) << 4)) = t0;
        *(bf16x8*)(smem + LDS_V + r1 * 128 + ((s1 ^ (r1 & 7)) << 4)) = t1;
    }
#pragma unroll
    for (int i = 0; i < 12; i++) a_lds[i * 256 + tid] = a_all[i * 256 + tid];
#pragma unroll
    for (int i = 0; i < 6; i++) bias_lds[i * 256 + tid] = gat_b_all[i * 256 + tid];
    if (tid < 96) ba_lds[tid] = ba_all[tid];
    {   // adjacency bitmasks via ballot
        const float* Ab = A + (size_t)g * 4096;
#pragma unroll
        for (int rr = 0; rr < 16; rr++) {
            int r = w * 16 + rr;
            unsigned long long m = __ballot(Ab[r * 64 + lane] > 0.f);
            if (lane == 0) Am[r] = m;
        }
    }
    __syncthreads();

    // valid-node mask (wave 0; consumed only in pool phase, after barriers)
    if (w == 0) {
        unsigned long long rowm = Am[lane];
        unsigned long long vm = __ballot((rowm >> lane) & 1ULL);
        if (lane == 0) {
            *(unsigned long long*)(smem + LDS_VALID) = vm;
            *(float*)(smem + LDS_VALID + 8) = 1.f / (float)__popcll(vm);
        }
    }

    // ---------------- embed GEMM: h = bf16(x @ Wemb^T) ----------------
    {
        f32x4 acc[4][4];
#pragma unroll
        for (int i = 0; i < 4; i++)
#pragma unroll
            for (int j = 0; j < 4; j++) acc[i][j] = (f32x4){0.f, 0.f, 0.f, 0.f};
#pragma unroll
        for (int ks = 0; ks < 2; ks++) {
            const int k0 = ks * 32 + q * 8;
            const int sl = ks * 4 + q;
            bf16x8 ah[4];
#pragma unroll
            for (int mf = 0; mf < 4; mf++) {
                int r = mf * 16 + d15;
                ah[mf] = *(const bf16x8*)(smem + LDS_V + r * 128 + ((sl ^ (r & 7)) << 4));
            }
#pragma unroll
            for (int nf = 0; nf < 4; nf++) {
                bf16x8 bh = *(const bf16x8*)(Wemb + (size_t)(w * 64 + nf * 16 + d15) * 64 + k0);
#pragma unroll
                for (int mf = 0; mf < 4; mf++)
                    acc[mf][nf] = MFMA16(ah[mf], bh, acc[mf][nf]);
            }
        }
#pragma unroll
        for (int nf = 0; nf < 4; nf++) {
            int d = w * 64 + nf * 16 + d15;
#pragma unroll
            for (int mf = 0; mf < 4; mf++)
#pragma unroll
                for (int rr = 0; rr < 4; rr++) {
                    int i = mf * 16 + q * 4 + rr;
                    *(__bf16*)(smem + h_off(i, d)) = (__bf16)acc[mf][nf][rr];
                }
        }
    }
    __syncthreads();   // h-tile complete; xb stage dead

    // ---------------- 6 GAT layers, h resident in LDS ----------------
#pragma unroll 1
    for (int l = 0; l < L_LAYERS; l++) {
        const __bf16* Wl = Wb_all + (size_t)l * WSLAB;

        f32x4 acc[4][4];
#pragma unroll
        for (int i = 0; i < 4; i++)
#pragma unroll
            for (int j = 0; j < 4; j++) acc[i][j] = (f32x4){0.f, 0.f, 0.f, 0.f};

        bf16x8 breg[3][4];
        auto loadB = [&](int buf, int ks) {
            const int k0 = ks * 32 + q * 8;
#pragma unroll
            for (int nf = 0; nf < 4; nf++)
                breg[buf][nf] = *(const bf16x8*)(Wl + (size_t)(w * 64 + nf * 16 + d15) * 256 + k0);
        };
        loadB(0, 0);
        loadB(1, 1);

#pragma unroll
        for (int ks = 0; ks < 8; ks++) {
            if (ks + 2 < 8) loadB((ks + 2) % 3, ks + 2);
            bf16x8 ah[4];
            const int sl = ks * 4 + q;
#pragma unroll
            for (int mf = 0; mf < 4; mf++) {
                int r = mf * 16 + d15;
                ah[mf] = *(const bf16x8*)(smem + r * 512 + ((sl ^ (r & 7)) << 4));
            }
#pragma unroll
            for (int nf = 0; nf < 4; nf++)
#pragma unroll
                for (int mf = 0; mf < 4; mf++)
                    acc[mf][nf] = MFMA16(ah[mf], breg[ks % 3][nf], acc[mf][nf]);
        }

        __syncthreads();   // all h-tile A-reads done before epilogue writes

        unsigned long long msk[4];
#pragma unroll
        for (int mf = 0; mf < 4; mf++) msk[mf] = Am[mf * 16 + d15];

#pragma unroll
        for (int hl = 0; hl < 2; hl++) {
            const int head = 2 * w + hl;

            // es/ed from acc in-register; E pre-scaled by log2(e)
#pragma unroll
            for (int sd = 0; sd < 2; sd++) {
                float a0 = a_lds[l * 512 + head * 64 + sd * 32 + d15];
                float a1 = a_lds[l * 512 + head * 64 + sd * 32 + 16 + d15];
                float tmp[4][4];
#pragma unroll
                for (int mf = 0; mf < 4; mf++)
#pragma unroll
                    for (int rr = 0; rr < 4; rr++)
                        tmp[mf][rr] = acc[mf][2 * hl][rr] * a0 + acc[mf][2 * hl + 1][rr] * a1;
#pragma unroll
                for (int off = 1; off <= 8; off <<= 1)
#pragma unroll
                    for (int mf = 0; mf < 4; mf++)
#pragma unroll
                        for (int rr = 0; rr < 4; rr++)
                            tmp[mf][rr] += __shfl_xor(tmp[mf][rr], off);
                float bac = ba_lds[l * 16 + 2 * head + sd];
                if (d15 == 0) {
#pragma unroll
                    for (int mf = 0; mf < 4; mf++)
#pragma unroll
                        for (int rr = 0; rr < 4; rr++)
                            E[(hl * 2 + sd) * 64 + mf * 16 + q * 4 + rr] =
                                (tmp[mf][rr] + bac) * LOG2E;
                }
            }

            // V fragments (wave-private, swizzled [d][j] bf16)
#pragma unroll
            for (int nfl = 0; nfl < 2; nfl++) {
                const int nf = hl * 2 + nfl;
                const int d  = nfl * 16 + d15;
                const float bv = bias_lds[l * 256 + w * 64 + nf * 16 + d15];
                char* vb = vwbase + d * 128;
#pragma unroll
                for (int mf = 0; mf < 4; mf++) {
                    int s   = mf * 2 + (q >> 1);
                    int off = ((s ^ (d & 7)) << 4) + (q & 1) * 8;
                    bf16x4 h4;
#pragma unroll
                    for (int rr = 0; rr < 4; rr++)
                        h4[rr] = (__bf16)(acc[mf][nf][rr] + bv);
                    *(bf16x4*)(vb + off) = h4;
                }
            }

            float ev = E[(hl * 2 + 1) * 64 + lane];
#pragma unroll
            for (int off = 32; off; off >>= 1) ev = fmaxf(ev, __shfl_xor(ev, off));

            float esi[4], mh[4];
#pragma unroll
            for (int mf = 0; mf < 4; mf++) {
                esi[mf] = E[(hl * 2) * 64 + mf * 16 + d15];
                mh[mf]  = leaky(esi[mf] + ev);
            }

            f32x4 pv[4][2];
#pragma unroll
            for (int mf = 0; mf < 4; mf++) {
                pv[mf][0] = (f32x4){0.f, 0.f, 0.f, 0.f};
                pv[mf][1] = (f32x4){0.f, 0.f, 0.f, 0.f};
            }
            float rs[4] = {0.f, 0.f, 0.f, 0.f};

#pragma unroll
            for (int ksj = 0; ksj < 2; ksj++) {
                const int j8 = ksj * 32 + q * 8;
                const int s  = ksj * 4 + q;
                bf16x8 vh[2];
#pragma unroll
                for (int nf2 = 0; nf2 < 2; nf2++) {
                    int d = nf2 * 16 + d15;
                    vh[nf2] = *(const bf16x8*)(vwbase + d * 128 + ((s ^ (d & 7)) << 4));
                }
                float edv[8];
#pragma unroll
                for (int e = 0; e < 8; e++) edv[e] = E[(hl * 2 + 1) * 64 + j8 + e];

#pragma unroll
                for (int mf = 0; mf < 4; mf++) {
                    unsigned int mb = (unsigned int)(msk[mf] >> j8) & 0xffu;
                    bf16x8 ph;
                    float rsum = 0.f;
#pragma unroll
                    for (int e = 0; e < 8; e++) {
                        float t = leaky(esi[mf] + edv[e]);   // log2-scaled
                        float p = ((mb >> e) & 1u)
                                    ? __builtin_amdgcn_exp2f(t - mh[mf]) : 0.f;
                        rsum += p;
                        ph[e] = (__bf16)p;
                    }
                    rs[mf] += rsum;
#pragma unroll
                    for (int nf2 = 0; nf2 < 2; nf2++)
                        pv[mf][nf2] = MFMA16(ph, vh[nf2], pv[mf][nf2]);
                }
            }

            // row sums -> 1/s
#pragma unroll
            for (int mf = 0; mf < 4; mf++) {
                float r = rs[mf];
                r += __shfl_xor(r, 16);
                r += __shfl_xor(r, 32);
                if (q == 0) invv[mf * 16 + d15] = (r > 0.f) ? 1.f / r : 0.f;
            }

            // epilogue: scale, residual (LDS), ELU, write back to LDS h-tile
#pragma unroll
            for (int mf = 0; mf < 4; mf++) {
#pragma unroll
                for (int nf2 = 0; nf2 < 2; nf2++) {
                    int d = head * 32 + nf2 * 16 + d15;
#pragma unroll
                    for (int rr = 0; rr < 4; rr++) {
                        int i = mf * 16 + q * 4 + rr;
                        float inv = invv[i];
                        int hoff = h_off(i, d);
                        float old = (float)*(const __bf16*)(smem + hoff);
                        float o = pv[mf][nf2][rr] * inv + old;
                        o = o > 0.f ? o : __expf(o) - 1.f;
                        *(__bf16*)(smem + hoff) = (__bf16)o;
                    }
                }
            }
        }
        __syncthreads();   // epilogue writes visible to next layer's GEMM
    }

    // ---------------- masked mean pool + MLP ----------------
    {
        unsigned long long vm = *(const unsigned long long*)(smem + LDS_VALID);
        float invc = *(const float*)(smem + LDS_VALID + 8);
        float gsum = 0.f;
#pragma unroll 8
        for (int n = 0; n < 64; n++)
            if ((vm >> n) & 1ULL)
                gsum += (float)*(const __bf16*)(smem + h_off(n, tid));

        float* gl = (float*)(smem + LDS_V);          // V area dead now
        float* z1 = (float*)(smem + LDS_V + 1024);
        float* z2 = (float*)(smem + LDS_V + 1536);
        gl[tid] = gsum * invc;
        __syncthreads();

        if (tid < 128) {
            const float* wr = W1 + tid * 256;
            float z = 0.f;
#pragma unroll 8
            for (int k = 0; k < 256; k += 4) {
                float4 wv = *(const float4*)&wr[k];
                z += wv.x * gl[k] + wv.y * gl[k + 1] + wv.z * gl[k + 2] + wv.w * gl[k + 3];
            }
            z += b1[tid];
            z1[tid] = z > 0.f ? z : 0.f;
        }
        __syncthreads();

        if (tid < 128) {
            const float* wr = W2 + tid * 128;
            float z = 0.f;
#pragma unroll 8
            for (int k = 0; k < 128; k += 4) {
                float4 wv = *(const float4*)&wr[k];
                z += wv.x * z1[k] + wv.y * z1[k + 1] + wv.z * z1[k + 2] + wv.w * z1[k + 3];
            }
            z += b2[tid];
            z2[tid] = z > 0.f ? z : 0.f;
        }
        __syncthreads();

        if (tid < 64) {
            float p = W3[tid] * z2[tid] + W3[tid + 64] * z2[tid + 64];
#pragma unroll
            for (int off = 32; off; off >>= 1) p += __shfl_down(p, off);
            if (tid == 0) {
                float z = p + b3[0];
                out[g] = (z > 0.f ? z : __expf(z) - 1.f) + 1.5f;
            }
        }
    }
}

// ---------------------------------------------------------------------------
extern "C" void kernel_launch(void* const* d_in, const int* in_sizes, int n_in,
                              void* d_out, int out_size, void* d_ws, size_t ws_size,
                              hipStream_t stream)
{
    const float* x      = (const float*)d_in[0];
    const float* A      = (const float*)d_in[1];
    const float* W_emb  = (const float*)d_in[2];
    const float* gat_W  = (const float*)d_in[3];
    const float* gat_b  = (const float*)d_in[4];
    const float* gat_a  = (const float*)d_in[5];
    const float* fc_W1  = (const float*)d_in[6];
    const float* fc_b1  = (const float*)d_in[7];
    const float* fc_W2  = (const float*)d_in[8];
    const float* fc_b2  = (const float*)d_in[9];
    const float* fc_W3  = (const float*)d_in[10];
    const float* fc_b3  = (const float*)d_in[11];
    float* out = (float*)d_out;

    // workspace (~17.6 MB):
    //   xb bf16 [131072][64]   @ 0          16777216
    //   Wemb_b [256][64]       @ 16777216   32768
    //   Wb [6][256][256] bf16  @ 16809984   786432
    //   ba [6][16] f32         @ 17596416   384
    char* ws = (char*)d_ws;
    __bf16* xb     = (__bf16*)ws;
    __bf16* Wemb_b = (__bf16*)(ws + 16777216);
    __bf16* Wb     = (__bf16*)(ws + 16809984);
    float*  ba     = (float*)(ws + 17596416);

    int conv_total = L_LAYERS * 65536 + L_LAYERS * 16;
    convert_weights<<<(conv_total + 255) / 256, 256, 0, stream>>>(
        W_emb, gat_W, gat_a, gat_b, Wemb_b, Wb, ba);
    convert_x<<<M_FULL * 64 / 256, 256, 0, stream>>>(x, xb);

    mega_gat<<<B_GRAPHS, 256, 0, stream>>>(
        A, xb, Wemb_b, Wb, gat_b, gat_a, ba,
        fc_W1, fc_b1, fc_W2, fc_b2, fc_W3, fc_b3, out);
}